// Round 2
// baseline (2547.109 us; speedup 1.0000x reference)
//
#include <hip/hip_runtime.h>
#include <hip/hip_bf16.h>
#include <stdint.h>

typedef float f32x4 __attribute__((ext_vector_type(4)));
typedef short short8 __attribute__((ext_vector_type(8)));
typedef unsigned short u16;

static __device__ __forceinline__ u16 f2bf(float f) {
    __hip_bfloat16 h = __float2bfloat16(f);
    return *reinterpret_cast<const u16*>(&h);
}

// ---------------- elementwise f32 -> bf16 cast (weights) ----------------
__global__ void k_cast(const float* __restrict__ in, u16* __restrict__ out, int n4) {
    int i = blockIdx.x * blockDim.x + threadIdx.x;
    if (i < n4) {
        float4 v = ((const float4*)in)[i];
        ushort4 o;
        o.x = f2bf(v.x); o.y = f2bf(v.y); o.z = f2bf(v.z); o.w = f2bf(v.w);
        ((ushort4*)out)[i] = o;
    }
}

// ------------- transpose+cast: f32 [b][512][4096] -> bf16 [b][4096][512] -------------
__global__ __launch_bounds__(256) void k_transpose(const float* __restrict__ in, u16* __restrict__ out) {
    __shared__ float t[64][65];
    int b = blockIdx.z;
    int c0 = blockIdx.y * 64;
    int n0 = blockIdx.x * 64;
    const float* ip = in + ((size_t)b * 512 + c0) * 4096 + n0;
#pragma unroll
    for (int i = 0; i < 16; ++i) {
        int idx = threadIdx.x + i * 256;
        int cl = idx >> 6, nl = idx & 63;
        t[cl][nl] = ip[(size_t)cl * 4096 + nl];
    }
    __syncthreads();
    u16* op = out + ((size_t)b * 4096 + n0) * 512 + c0;
#pragma unroll
    for (int i = 0; i < 16; ++i) {
        int idx = threadIdx.x + i * 256;
        int nr = idx >> 6, cc = idx & 63;
        op[(size_t)nr * 512 + cc] = f2bf(t[cc][nr]);
    }
}

// ------------- content per-(b,c) mean / rstd (ddof=1, +eps) -------------
__global__ __launch_bounds__(256) void k_cstats(const float* __restrict__ content, float* __restrict__ cstat) {
    int c = blockIdx.x, b = blockIdx.y;
    const float4* r4 = (const float4*)(content + ((size_t)b * 512 + c) * 4096);
    float s = 0.f, ss = 0.f;
    for (int i = threadIdx.x; i < 1024; i += 256) {
        float4 v = r4[i];
        s += v.x + v.y + v.z + v.w;
        ss += v.x * v.x + v.y * v.y + v.z * v.z + v.w * v.w;
    }
#pragma unroll
    for (int k = 1; k < 64; k <<= 1) { s += __shfl_xor(s, k); ss += __shfl_xor(ss, k); }
    __shared__ float ls[4], lss[4];
    int w = threadIdx.x >> 6;
    if ((threadIdx.x & 63) == 0) { ls[w] = s; lss[w] = ss; }
    __syncthreads();
    if (threadIdx.x == 0) {
        s = ls[0] + ls[1] + ls[2] + ls[3];
        ss = lss[0] + lss[1] + lss[2] + lss[3];
        float mu = s / 4096.f;
        float var = (ss - 4096.f * mu * mu) / 4095.f;
        cstat[((size_t)b * 512 + c) * 2] = mu;
        cstat[((size_t)b * 512 + c) * 2 + 1] = rsqrtf(var + 1e-5f);
    }
}

// ------------- conv1x1, pixel-major output: out[b][n][o] = sum_c XT[b][n][c]*W[o][c] + bias[o] -------------
__global__ __launch_bounds__(256) void k_convP(const u16* __restrict__ XT, const u16* __restrict__ Wb,
                                               const float* __restrict__ bias, u16* __restrict__ out) {
    int b = blockIdx.z;
    int n0 = blockIdx.x * 64, o0 = blockIdx.y * 64;
    int lane = threadIdx.x & 63, w = threadIdx.x >> 6;
    int l15 = lane & 15, l4 = lane >> 4;
    const u16* ap = XT + ((size_t)b * 4096 + n0 + w * 16 + l15) * 512 + l4 * 8;
    f32x4 acc[4] = {{0,0,0,0},{0,0,0,0},{0,0,0,0},{0,0,0,0}};
#pragma unroll
    for (int kk = 0; kk < 16; ++kk) {
        short8 a = *(const short8*)(ap + kk * 32);
#pragma unroll
        for (int bo = 0; bo < 4; ++bo) {
            const u16* bp = Wb + ((size_t)(o0 + bo * 16 + l15)) * 512 + kk * 32 + l4 * 8;
            short8 bb = *(const short8*)bp;
            acc[bo] = __builtin_amdgcn_mfma_f32_16x16x32_bf16(a, bb, acc[bo], 0, 0, 0);
        }
    }
#pragma unroll
    for (int bo = 0; bo < 4; ++bo) {
        float bv = bias[o0 + bo * 16 + l15];
#pragma unroll
        for (int r = 0; r < 4; ++r) {
            int n = n0 + w * 16 + l4 * 4 + r;
            out[((size_t)b * 4096 + n) * 512 + o0 + bo * 16 + l15] = f2bf(acc[bo][r] + bv);
        }
    }
}

// ------------- conv1x1, channel-major output + squares: out[b][o][m], out[b][o+512][m] = val^2 -------------
__global__ __launch_bounds__(256) void k_convH(const u16* __restrict__ ST, const u16* __restrict__ Wb,
                                               const float* __restrict__ bias, u16* __restrict__ out) {
    int b = blockIdx.z;
    int o0 = blockIdx.x * 64, m0 = blockIdx.y * 64;
    int lane = threadIdx.x & 63, w = threadIdx.x >> 6;
    int l15 = lane & 15, l4 = lane >> 4;
    const u16* ap = Wb + ((size_t)(o0 + w * 16 + l15)) * 512 + l4 * 8;
    f32x4 acc[4] = {{0,0,0,0},{0,0,0,0},{0,0,0,0},{0,0,0,0}};
#pragma unroll
    for (int kk = 0; kk < 16; ++kk) {
        short8 a = *(const short8*)(ap + kk * 32);
#pragma unroll
        for (int mb = 0; mb < 4; ++mb) {
            const u16* bp = ST + ((size_t)b * 4096 + m0 + mb * 16 + l15) * 512 + kk * 32 + l4 * 8;
            short8 bb = *(const short8*)bp;
            acc[mb] = __builtin_amdgcn_mfma_f32_16x16x32_bf16(a, bb, acc[mb], 0, 0, 0);
        }
    }
#pragma unroll
    for (int r = 0; r < 4; ++r) {
        int o = o0 + w * 16 + l4 * 4 + r;
        float bv = bias[o];
#pragma unroll
        for (int mb = 0; mb < 4; ++mb) {
            float v = acc[mb][r] + bv;
            size_t base = ((size_t)b * 1024 + o) * 4096 + m0 + mb * 16 + l15;
            out[base] = f2bf(v);
            out[base + (size_t)512 * 4096] = f2bf(v * v);
        }
    }
}

// ------------- fused two-pass attention + normalization epilogue -------------
// grid (128 query-tiles of 32, 4 batches), block 512 (8 waves)
// wave w: R=w&1 row-strip (16 rows), MB=w>>1 QK m-block / PV c-chunk
__global__ __launch_bounds__(512, 2) void k_attn(
    const u16* __restrict__ Q, const u16* __restrict__ G, const u16* __restrict__ H,
    const float* __restrict__ wmix, const float* __restrict__ content,
    const float* __restrict__ cstat, float* __restrict__ out) {
    int b = blockIdx.y;
    int n0 = blockIdx.x * 32;
    int lane = threadIdx.x & 63, w = threadIdx.x >> 6;
    int l15 = lane & 15, l4 = lane >> 4;
    int R = w & 1, MB = w >> 1;

    float wa = wmix[0], wbv = wmix[1];
    float wmx = fmaxf(wa, wbv);
    float e0 = __expf(wa - wmx), e1 = __expf(wbv - wmx);
    float w0 = e0 / (e0 + e1), w1 = e1 / (e0 + e1);

    // Q fragments: wave's 16-row strip, full K=512, kept in registers (64 VGPR)
    const u16* qp = Q + ((size_t)b * 4096 + n0 + R * 16 + l15) * 512 + l4 * 8;
    short8 q[16];
#pragma unroll
    for (int kk = 0; kk < 16; ++kk) q[kk] = *(const short8*)(qp + kk * 32);

    const u16* gbase = G + ((size_t)b * 4096 + MB * 16 + l15) * 512 + l4 * 8;

    // ---- pass 1: per-lane online softmax stats (dense + sparse), no shuffles in loop ----
    float md[4], sd[4], msp[4], ssp[4];
#pragma unroll
    for (int r = 0; r < 4; ++r) { md[r] = -1e30f; sd[r] = 0.f; msp[r] = -1e30f; ssp[r] = 0.f; }

    for (int mc = 0; mc < 64; ++mc) {
        f32x4 acc = {0, 0, 0, 0};
        const u16* gp = gbase + (size_t)mc * 64 * 512;
#pragma unroll
        for (int kk = 0; kk < 16; ++kk) {
            short8 g = *(const short8*)(gp + kk * 32);
            acc = __builtin_amdgcn_mfma_f32_16x16x32_bf16(q[kk], g, acc, 0, 0, 0);
        }
#pragma unroll
        for (int r = 0; r < 4; ++r) {
            float v = acc[r];
            float mn = fmaxf(md[r], v);
            sd[r] = sd[r] * __expf(md[r] - mn) + __expf(v - mn);
            md[r] = mn;
            float vs = fmaxf(v, 0.f);
            float mn2 = fmaxf(msp[r], vs);
            ssp[r] = ssp[r] * __expf(msp[r] - mn2) + __expf(vs - mn2);
            msp[r] = mn2;
        }
    }
    // merge across the 16 lanes of each row-group
#pragma unroll
    for (int r = 0; r < 4; ++r) {
#pragma unroll
        for (int k = 1; k < 16; k <<= 1) {
            float mo = __shfl_xor(md[r], k), so = __shfl_xor(sd[r], k);
            float mn = fmaxf(md[r], mo);
            sd[r] = sd[r] * __expf(md[r] - mn) + so * __expf(mo - mn);
            md[r] = mn;
            mo = __shfl_xor(msp[r], k); so = __shfl_xor(ssp[r], k);
            mn = fmaxf(msp[r], mo);
            ssp[r] = ssp[r] * __expf(msp[r] - mn) + so * __expf(mo - mn);
            msp[r] = mn;
        }
    }
    // merge across the 4 m-block waves of each strip via LDS
    __shared__ float smd[2][4][16], ssd_[2][4][16], smsp[2][4][16], sssp[2][4][16];
    if (l15 == 0) {
#pragma unroll
        for (int r = 0; r < 4; ++r) {
            int row = l4 * 4 + r;
            smd[R][MB][row] = md[r]; ssd_[R][MB][row] = sd[r];
            smsp[R][MB][row] = msp[r]; sssp[R][MB][row] = ssp[r];
        }
    }
    __syncthreads();
    float isd[4], issp[4];
#pragma unroll
    for (int r = 0; r < 4; ++r) {
        int row = l4 * 4 + r;
        float M = -1e30f, S = 0.f;
#pragma unroll
        for (int i = 0; i < 4; ++i) {
            float m2 = smd[R][i][row], s2 = ssd_[R][i][row];
            float mn = fmaxf(M, m2);
            S = S * __expf(M - mn) + s2 * __expf(m2 - mn);
            M = mn;
        }
        md[r] = M; isd[r] = 1.f / S;
        M = -1e30f; S = 0.f;
#pragma unroll
        for (int i = 0; i < 4; ++i) {
            float m2 = smsp[R][i][row], s2 = sssp[R][i][row];
            float mn = fmaxf(M, m2);
            S = S * __expf(M - mn) + s2 * __expf(m2 - mn);
            M = mn;
        }
        msp[r] = M; issp[r] = 1.f / S;
    }
    __syncthreads();

    // ---- pass 2: recompute raw, outer weights e=exp(t) (t in (0,1], no max needed), PV ----
    __shared__ __align__(16) u16 elds[2][2048];  // double-buffered 32x64 e-tile, XOR-swizzled
    f32x4 pv[16];
#pragma unroll
    for (int i = 0; i < 16; ++i) pv[i] = (f32x4){0, 0, 0, 0};
    float Z[4] = {0, 0, 0, 0};

    for (int mc = 0; mc < 64; ++mc) {
        int buf = mc & 1;
        f32x4 acc = {0, 0, 0, 0};
        const u16* gp = gbase + (size_t)mc * 64 * 512;
#pragma unroll
        for (int kk = 0; kk < 16; ++kk) {
            short8 g = *(const short8*)(gp + kk * 32);
            acc = __builtin_amdgcn_mfma_f32_16x16x32_bf16(q[kk], g, acc, 0, 0, 0);
        }
        char* eb = (char*)&elds[buf][0];
#pragma unroll
        for (int r = 0; r < 4; ++r) {
            float v = acc[r];
            float ed = __expf(v - md[r]) * isd[r];
            float es = __expf(fmaxf(v, 0.f) - msp[r]) * issp[r];
            float t = w0 * ed + w1 * es;
            float e = __expf(t);
            Z[r] += e;
            int row = R * 16 + l4 * 4 + r;
            unsigned byte = (unsigned)(row * 128 + (MB * 16 + l15) * 2) ^ (unsigned)((row & 7) << 4);
            *(u16*)(eb + byte) = f2bf(e);
        }
        __syncthreads();
        // PV: A-frags from swizzled LDS e-tile, B-frags straight from global H (channel-major)
        short8 af[2];
        int rowA = R * 16 + l15;
#pragma unroll
        for (int kb = 0; kb < 2; ++kb) {
            unsigned byte = (unsigned)(rowA * 128 + kb * 64 + l4 * 16) ^ (unsigned)((rowA & 7) << 4);
            af[kb] = *(const short8*)(eb + byte);
        }
        const u16* hbase = H + (size_t)b * 1024 * 4096 + (size_t)mc * 64 + l4 * 8;
#pragma unroll
        for (int half = 0; half < 2; ++half) {
#pragma unroll
            for (int cf = 0; cf < 8; ++cf) {
                int c = half * 512 + MB * 128 + cf * 16 + l15;
                const u16* hp = hbase + (size_t)c * 4096;
#pragma unroll
                for (int kb = 0; kb < 2; ++kb) {
                    short8 hh = *(const short8*)(hp + kb * 32);
                    pv[half * 8 + cf] = __builtin_amdgcn_mfma_f32_16x16x32_bf16(af[kb], hh, pv[half * 8 + cf], 0, 0, 0);
                }
            }
        }
    }

    // ---- Z reduction: 16 lanes, then 4 waves ----
#pragma unroll
    for (int r = 0; r < 4; ++r)
#pragma unroll
        for (int k = 1; k < 16; k <<= 1) Z[r] += __shfl_xor(Z[r], k);
    __shared__ float zl[2][4][16];
    if (l15 == 0) {
#pragma unroll
        for (int r = 0; r < 4; ++r) zl[R][MB][l4 * 4 + r] = Z[r];
    }
    __syncthreads();
    float iZ[4];
#pragma unroll
    for (int r = 0; r < 4; ++r) {
        int row = l4 * 4 + r;
        iZ[r] = 1.f / (zl[R][0][row] + zl[R][1][row] + zl[R][2][row] + zl[R][3][row]);
    }

    // ---- epilogue: mean/std + fused mean_variance_norm(content) ----
#pragma unroll
    for (int cf = 0; cf < 8; ++cf) {
        int c = MB * 128 + cf * 16 + l15;
        float mu = cstat[((size_t)b * 512 + c) * 2];
        float rstd = cstat[((size_t)b * 512 + c) * 2 + 1];
        const float* cp = content + ((size_t)b * 512 + c) * 4096 + n0 + R * 16;
        float* op = out + ((size_t)b * 512 + c) * 4096 + n0 + R * 16;
#pragma unroll
        for (int r = 0; r < 4; ++r) {
            int n = l4 * 4 + r;
            float mean = pv[cf][r] * iZ[r];
            float sec = pv[8 + cf][r] * iZ[r];
            float stdv = sqrtf(fmaxf(sec - mean * mean, 0.f));
            op[n] = stdv * (cp[n] - mu) * rstd + mean;
        }
    }
}

extern "C" void kernel_launch(void* const* d_in, const int* in_sizes, int n_in,
                              void* d_out, int out_size, void* d_ws, size_t ws_size,
                              hipStream_t stream) {
    (void)in_sizes; (void)n_in; (void)out_size; (void)ws_size;
    const float* content = (const float*)d_in[0];
    const float* style   = (const float*)d_in[1];
    const float* ckey    = (const float*)d_in[2];
    const float* skey    = (const float*)d_in[3];
    const float* f_w = (const float*)d_in[4];
    const float* f_b = (const float*)d_in[5];
    const float* g_w = (const float*)d_in[6];
    const float* g_b = (const float*)d_in[7];
    const float* h_w = (const float*)d_in[8];
    const float* h_b = (const float*)d_in[9];
    const float* wmix = (const float*)d_in[10];
    float* out = (float*)d_out;

    // Workspace layout (82 MB total). Hb aliases ckT+skT: both convP launches
    // (which consume ckT/skT) complete before convH writes Hb — same-stream
    // kernels serialize, so the alias is safe and saves 32 MB+ of footprint.
    char* ws = (char*)d_ws;
    u16* ckT = (u16*)(ws + 0);                      // 16 MB  bf16 [b][n][512]
    u16* skT = (u16*)(ws + (size_t)16 * 1048576);   // 16 MB
    u16* stT = (u16*)(ws + (size_t)32 * 1048576);   // 16 MB
    u16* fwB = (u16*)(ws + (size_t)48 * 1048576);   // 512 KB
    u16* gwB = (u16*)(ws + (size_t)48 * 1048576 + 524288);
    u16* hwB = (u16*)(ws + (size_t)48 * 1048576 + 1048576);
    float* cst = (float*)(ws + (size_t)48 * 1048576 + 1572864);  // 16 KB
    u16* Qb  = (u16*)(ws + (size_t)50 * 1048576);   // 16 MB  Fm pixel-major
    u16* Gb  = (u16*)(ws + (size_t)66 * 1048576);   // 16 MB  Gm pixel-major
    u16* Hb  = (u16*)(ws + 0);                      // 32 MB  [Hm;Hm^2] channel-major (aliases ckT/skT)

    k_cast<<<256, 256, 0, stream>>>(f_w, fwB, 65536);
    k_cast<<<256, 256, 0, stream>>>(g_w, gwB, 65536);
    k_cast<<<256, 256, 0, stream>>>(h_w, hwB, 65536);
    k_transpose<<<dim3(64, 8, 4), 256, 0, stream>>>(ckey, ckT);
    k_transpose<<<dim3(64, 8, 4), 256, 0, stream>>>(skey, skT);
    k_transpose<<<dim3(64, 8, 4), 256, 0, stream>>>(style, stT);
    k_cstats<<<dim3(512, 4), 256, 0, stream>>>(content, cst);
    k_convP<<<dim3(64, 8, 4), 256, 0, stream>>>(ckT, fwB, f_b, Qb);
    k_convP<<<dim3(64, 8, 4), 256, 0, stream>>>(skT, gwB, g_b, Gb);
    k_convH<<<dim3(8, 64, 4), 256, 0, stream>>>(stT, hwB, h_b, Hb);
    k_attn<<<dim3(128, 4), 512, 0, stream>>>(Qb, Gb, Hb, wmix, content, cst, out);
}

// Round 4
// 1187.164 us; speedup vs baseline: 2.1455x; 2.1455x over previous
//
#include <hip/hip_runtime.h>
#include <hip/hip_bf16.h>
#include <stdint.h>

typedef float f32x4 __attribute__((ext_vector_type(4)));
typedef short short8 __attribute__((ext_vector_type(8)));
typedef unsigned short u16;

static __device__ __forceinline__ u16 f2bf(float f) {
    __hip_bfloat16 h = __float2bfloat16(f);
    return *reinterpret_cast<const u16*>(&h);
}

// async global->LDS, 16B per lane: LDS dest = wave-uniform base + lane*16,
// global src is per-lane (carries the swizzle).
static __device__ __forceinline__ void gload16(const void* g, void* l) {
    __builtin_amdgcn_global_load_lds((const __attribute__((address_space(1))) void*)g,
                                     (__attribute__((address_space(3))) void*)l, 16, 0, 0);
}

// ---------------- elementwise f32 -> bf16 cast (weights) ----------------
__global__ void k_cast(const float* __restrict__ in, u16* __restrict__ out, int n4) {
    int i = blockIdx.x * blockDim.x + threadIdx.x;
    if (i < n4) {
        float4 v = ((const float4*)in)[i];
        ushort4 o;
        o.x = f2bf(v.x); o.y = f2bf(v.y); o.z = f2bf(v.z); o.w = f2bf(v.w);
        ((ushort4*)out)[i] = o;
    }
}

// ------------- transpose+cast: f32 [b][512][4096] -> bf16 [b][4096][512] -------------
__global__ __launch_bounds__(256) void k_transpose(const float* __restrict__ in, u16* __restrict__ out) {
    __shared__ float t[64][65];
    int b = blockIdx.z;
    int c0 = blockIdx.y * 64;
    int n0 = blockIdx.x * 64;
    const float* ip = in + ((size_t)b * 512 + c0) * 4096 + n0;
#pragma unroll
    for (int i = 0; i < 16; ++i) {
        int idx = threadIdx.x + i * 256;
        int cl = idx >> 6, nl = idx & 63;
        t[cl][nl] = ip[(size_t)cl * 4096 + nl];
    }
    __syncthreads();
    u16* op = out + ((size_t)b * 4096 + n0) * 512 + c0;
#pragma unroll
    for (int i = 0; i < 16; ++i) {
        int idx = threadIdx.x + i * 256;
        int nr = idx >> 6, cc = idx & 63;
        op[(size_t)nr * 512 + cc] = f2bf(t[cc][nr]);
    }
}

// ------------- content per-(b,c) mean / rstd (ddof=1, +eps) -------------
__global__ __launch_bounds__(256) void k_cstats(const float* __restrict__ content, float* __restrict__ cstat) {
    int c = blockIdx.x, b = blockIdx.y;
    const float4* r4 = (const float4*)(content + ((size_t)b * 512 + c) * 4096);
    float s = 0.f, ss = 0.f;
    for (int i = threadIdx.x; i < 1024; i += 256) {
        float4 v = r4[i];
        s += v.x + v.y + v.z + v.w;
        ss += v.x * v.x + v.y * v.y + v.z * v.z + v.w * v.w;
    }
#pragma unroll
    for (int k = 1; k < 64; k <<= 1) { s += __shfl_xor(s, k); ss += __shfl_xor(ss, k); }
    __shared__ float ls[4], lss[4];
    int w = threadIdx.x >> 6;
    if ((threadIdx.x & 63) == 0) { ls[w] = s; lss[w] = ss; }
    __syncthreads();
    if (threadIdx.x == 0) {
        s = ls[0] + ls[1] + ls[2] + ls[3];
        ss = lss[0] + lss[1] + lss[2] + lss[3];
        float mu = s / 4096.f;
        float var = (ss - 4096.f * mu * mu) / 4095.f;
        cstat[((size_t)b * 512 + c) * 2] = mu;
        cstat[((size_t)b * 512 + c) * 2 + 1] = rsqrtf(var + 1e-5f);
    }
}

// ------------- conv1x1, pixel-major output: out[b][n][o] = sum_c XT[b][n][c]*W[o][c] + bias[o] -------------
__global__ __launch_bounds__(256) void k_convP(const u16* __restrict__ XT, const u16* __restrict__ Wb,
                                               const float* __restrict__ bias, u16* __restrict__ out) {
    int b = blockIdx.z;
    int n0 = blockIdx.x * 64, o0 = blockIdx.y * 64;
    int lane = threadIdx.x & 63, w = threadIdx.x >> 6;
    int l15 = lane & 15, l4 = lane >> 4;
    const u16* ap = XT + ((size_t)b * 4096 + n0 + w * 16 + l15) * 512 + l4 * 8;
    f32x4 acc[4] = {{0,0,0,0},{0,0,0,0},{0,0,0,0},{0,0,0,0}};
#pragma unroll
    for (int kk = 0; kk < 16; ++kk) {
        short8 a = *(const short8*)(ap + kk * 32);
#pragma unroll
        for (int bo = 0; bo < 4; ++bo) {
            const u16* bp = Wb + ((size_t)(o0 + bo * 16 + l15)) * 512 + kk * 32 + l4 * 8;
            short8 bb = *(const short8*)bp;
            acc[bo] = __builtin_amdgcn_mfma_f32_16x16x32_bf16(a, bb, acc[bo], 0, 0, 0);
        }
    }
#pragma unroll
    for (int bo = 0; bo < 4; ++bo) {
        float bv = bias[o0 + bo * 16 + l15];
#pragma unroll
        for (int r = 0; r < 4; ++r) {
            int n = n0 + w * 16 + l4 * 4 + r;
            out[((size_t)b * 4096 + n) * 512 + o0 + bo * 16 + l15] = f2bf(acc[bo][r] + bv);
        }
    }
}

// ------------- conv1x1, channel-major output + squares: out[b][o][m], out[b][o+512][m] = val^2 -------------
__global__ __launch_bounds__(256) void k_convH(const u16* __restrict__ ST, const u16* __restrict__ Wb,
                                               const float* __restrict__ bias, u16* __restrict__ out) {
    int b = blockIdx.z;
    int o0 = blockIdx.x * 64, m0 = blockIdx.y * 64;
    int lane = threadIdx.x & 63, w = threadIdx.x >> 6;
    int l15 = lane & 15, l4 = lane >> 4;
    const u16* ap = Wb + ((size_t)(o0 + w * 16 + l15)) * 512 + l4 * 8;
    f32x4 acc[4] = {{0,0,0,0},{0,0,0,0},{0,0,0,0},{0,0,0,0}};
#pragma unroll
    for (int kk = 0; kk < 16; ++kk) {
        short8 a = *(const short8*)(ap + kk * 32);
#pragma unroll
        for (int mb = 0; mb < 4; ++mb) {
            const u16* bp = ST + ((size_t)b * 4096 + m0 + mb * 16 + l15) * 512 + kk * 32 + l4 * 8;
            short8 bb = *(const short8*)bp;
            acc[mb] = __builtin_amdgcn_mfma_f32_16x16x32_bf16(a, bb, acc[mb], 0, 0, 0);
        }
    }
#pragma unroll
    for (int r = 0; r < 4; ++r) {
        int o = o0 + w * 16 + l4 * 4 + r;
        float bv = bias[o];
#pragma unroll
        for (int mb = 0; mb < 4; ++mb) {
            float v = acc[mb][r] + bv;
            size_t base = ((size_t)b * 1024 + o) * 4096 + m0 + mb * 16 + l15;
            out[base] = f2bf(v);
            out[base + (size_t)512 * 4096] = f2bf(v * v);
        }
    }
}

// ------------- fused two-pass attention + normalization epilogue (v2) -------------
// grid 256 blocks (1/CU), 512 threads (8 waves), QBLK=64, KVBLK=64.
// XCD-aware decode: XCD k serves batch k>>1 (12 MB streaming set per XCD L2).
// QK phase: wave (R=w>>1, MB=w&1) computes 16q x 32kv; G-tile double-buffered in
// LDS via global_load_lds (pre-swizzled source, XOR-swizzled ds_read).
// PV phase: wave w owns 64 mean-channels + matching 64 sec-channels.
__global__ __launch_bounds__(512, 2) void k_attn(
    const u16* __restrict__ Q, const u16* __restrict__ G, const u16* __restrict__ H,
    const float* __restrict__ wmix, const float* __restrict__ content,
    const float* __restrict__ cstat, float* __restrict__ out) {

    __shared__ __align__(16) u16 gtile[2][64 * 512];   // 128 KB, double-buffered G-tile
    __shared__ __align__(16) u16 etile[64 * 64];       // 8 KB e-tile
    __shared__ float smd[4][2][16], ssd_[4][2][16], smsp[4][2][16], sssp[4][2][16];
    __shared__ float zl[4][2][16];

    int bid = blockIdx.x;
    int b = (bid & 7) >> 1;                       // batch per XCD-pair
    int qt = ((bid & 1) << 5) | (bid >> 3);       // q-tile 0..63
    int n0 = qt * 64;
    int tid = threadIdx.x;
    int lane = tid & 63, w = tid >> 6;
    int l15 = lane & 15, l4 = lane >> 4;
    int R = w >> 1, MB = w & 1;

    float wa = wmix[0], wbv = wmix[1];
    float wmx = fmaxf(wa, wbv);
    float e0 = __expf(wa - wmx), e1 = __expf(wbv - wmx);
    float w0 = e0 / (e0 + e1), w1 = e1 / (e0 + e1);

    // Q fragments: wave's 16-row strip (QK layout), full K=512, in registers (64 VGPR)
    const u16* qp = Q + ((size_t)b * 4096 + n0 + R * 16 + l15) * 512 + l4 * 8;
    short8 q[16];
#pragma unroll
    for (int kk = 0; kk < 16; ++kk) q[kk] = *(const short8*)(qp + kk * 32);

    const char* gbat = (const char*)(G + (size_t)b * 4096 * 512);

    // stage G-tile [64 rows x 1024 B] for kv-chunk mc into gtile[buf].
    // LDS dest linear; global source pre-swizzled (rule 21: swz both-sides-or-neither).
#define STAGE(buf, mc)                                                                 \
    {                                                                                  \
        _Pragma("unroll")                                                              \
        for (int j = 0; j < 8; ++j) {                                                  \
            int row = j * 8 + w;                                                       \
            const char* src = gbat + ((size_t)((mc) * 64 + row)) * 1024                \
                              + ((lane * 16) ^ ((row & 7) << 4));                      \
            gload16(src, (char*)&gtile[buf][0] + row * 1024);                          \
        }                                                                              \
    }

    // QK: 32 MFMA from swizzled LDS tile into acc[2] (16q x 2x16kv)
#define QK(buf, acc)                                                                   \
    {                                                                                  \
        const char* gt = (const char*)&gtile[buf][0];                                  \
        _Pragma("unroll")                                                              \
        for (int kk = 0; kk < 16; ++kk) {                                              \
            _Pragma("unroll")                                                          \
            for (int t = 0; t < 2; ++t) {                                              \
                int row = MB * 32 + t * 16 + l15;                                      \
                int y = (kk * 64 + l4 * 16) ^ ((row & 7) << 4);                        \
                short8 g = *(const short8*)(gt + row * 1024 + y);                      \
                acc[t] = __builtin_amdgcn_mfma_f32_16x16x32_bf16(q[kk], g, acc[t], 0, 0, 0); \
            }                                                                          \
        }                                                                              \
    }

    // ---- pass 1: online softmax stats (dense + relu) ----
    float md[4], sd[4], ms[4], ss[4];
#pragma unroll
    for (int r = 0; r < 4; ++r) { md[r] = -1e30f; sd[r] = 0.f; ms[r] = -1e30f; ss[r] = 0.f; }

    STAGE(0, 0);
    __syncthreads();
    for (int mc = 0; mc < 64; ++mc) {
        int buf = mc & 1;
        if (mc < 63) STAGE(buf ^ 1, mc + 1);
        f32x4 acc[2] = {{0,0,0,0},{0,0,0,0}};
        QK(buf, acc);
#pragma unroll
        for (int t = 0; t < 2; ++t)
#pragma unroll
            for (int r = 0; r < 4; ++r) {
                float v = acc[t][r];
                float mn = fmaxf(md[r], v);
                sd[r] = sd[r] * __expf(md[r] - mn) + __expf(v - mn);
                md[r] = mn;
                float vs = fmaxf(v, 0.f);
                mn = fmaxf(ms[r], vs);
                ss[r] = ss[r] * __expf(ms[r] - mn) + __expf(vs - mn);
                ms[r] = mn;
            }
        __syncthreads();   // drains stage loads (vmcnt) + flips buffer
    }

    // merge across 16 kv-lanes
#pragma unroll
    for (int r = 0; r < 4; ++r) {
#pragma unroll
        for (int k = 1; k < 16; k <<= 1) {
            float mo = __shfl_xor(md[r], k), so = __shfl_xor(sd[r], k);
            float mn = fmaxf(md[r], mo);
            sd[r] = sd[r] * __expf(md[r] - mn) + so * __expf(mo - mn);
            md[r] = mn;
            mo = __shfl_xor(ms[r], k); so = __shfl_xor(ss[r], k);
            mn = fmaxf(ms[r], mo);
            ss[r] = ss[r] * __expf(ms[r] - mn) + so * __expf(mo - mn);
            ms[r] = mn;
        }
    }
    // merge across the 2 MB-waves of each strip
    if (l15 == 0) {
#pragma unroll
        for (int r = 0; r < 4; ++r) {
            int row = l4 * 4 + r;
            smd[R][MB][row] = md[r]; ssd_[R][MB][row] = sd[r];
            smsp[R][MB][row] = ms[r]; sssp[R][MB][row] = ss[r];
        }
    }
    __syncthreads();
    float isd[4], iss[4];
#pragma unroll
    for (int r = 0; r < 4; ++r) {
        int row = l4 * 4 + r;
        float m0_ = smd[R][0][row], s0_ = ssd_[R][0][row];
        float m1_ = smd[R][1][row], s1_ = ssd_[R][1][row];
        float mn = fmaxf(m0_, m1_);
        isd[r] = 1.f / (s0_ * __expf(m0_ - mn) + s1_ * __expf(m1_ - mn));
        md[r] = mn;
        m0_ = smsp[R][0][row]; s0_ = sssp[R][0][row];
        m1_ = smsp[R][1][row]; s1_ = sssp[R][1][row];
        mn = fmaxf(m0_, m1_);
        iss[r] = 1.f / (s0_ * __expf(m0_ - mn) + s1_ * __expf(m1_ - mn));
        ms[r] = mn;
    }

    // ---- pass 2: recompute raw, e = exp(w0*ed + w1*es) in (1,e], PV ----
    f32x4 pv[32];
#pragma unroll
    for (int i = 0; i < 32; ++i) pv[i] = (f32x4){0, 0, 0, 0};
    float Z[4] = {0, 0, 0, 0};

    STAGE(0, 0);
    __syncthreads();
    for (int mc = 0; mc < 64; ++mc) {
        int buf = mc & 1;
        if (mc < 63) STAGE(buf ^ 1, mc + 1);
        f32x4 acc[2] = {{0,0,0,0},{0,0,0,0}};
        QK(buf, acc);
        char* eb = (char*)&etile[0];
#pragma unroll
        for (int t = 0; t < 2; ++t)
#pragma unroll
            for (int r = 0; r < 4; ++r) {
                float v = acc[t][r];
                float ed = __expf(v - md[r]) * isd[r];
                float es = __expf(fmaxf(v, 0.f) - ms[r]) * iss[r];
                float e = __expf(w0 * ed + w1 * es);
                Z[r] += e;
                int row = R * 16 + l4 * 4 + r;
                int y = ((MB * 32 + t * 16 + l15) * 2) ^ ((row & 7) << 4);
                *(u16*)(eb + row * 128 + y) = f2bf(e);
            }
        // mid barrier: LDS-only drain — keep stage loads (vmcnt) in flight!
        asm volatile("s_waitcnt lgkmcnt(0)" ::: "memory");
        __builtin_amdgcn_s_barrier();
        __builtin_amdgcn_sched_barrier(0);

        // PV: wave owns channels [w*64, w*64+64) (mean) and +512 (second moment)
        const u16* hb = H + (size_t)b * 1024 * 4096 + (size_t)mc * 64 + l4 * 8;
#pragma unroll
        for (int ks = 0; ks < 2; ++ks) {
            short8 af[4];
#pragma unroll
            for (int qf = 0; qf < 4; ++qf) {
                int rowA = qf * 16 + l15;
                int y = (ks * 64 + l4 * 16) ^ ((rowA & 7) << 4);
                af[qf] = *(const short8*)(eb + rowA * 128 + y);
            }
#pragma unroll
            for (int cf = 0; cf < 8; ++cf) {
                int c = (cf < 4) ? (w * 64 + cf * 16 + l15) : (512 + w * 64 + (cf - 4) * 16 + l15);
                short8 hh = *(const short8*)(hb + (size_t)c * 4096 + ks * 32);
#pragma unroll
                for (int qf = 0; qf < 4; ++qf)
                    pv[qf * 8 + cf] = __builtin_amdgcn_mfma_f32_16x16x32_bf16(af[qf], hh, pv[qf * 8 + cf], 0, 0, 0);
            }
        }
        __syncthreads();   // e-tile reuse + buffer flip + stage drain
    }

    // ---- Z reduction ----
#pragma unroll
    for (int r = 0; r < 4; ++r)
#pragma unroll
        for (int k = 1; k < 16; k <<= 1) Z[r] += __shfl_xor(Z[r], k);
    if (l15 == 0) {
#pragma unroll
        for (int r = 0; r < 4; ++r) zl[R][MB][l4 * 4 + r] = Z[r];
    }
    __syncthreads();

    // ---- epilogue: mean/std + fused mean_variance_norm(content), float4 I/O ----
#pragma unroll
    for (int qf = 0; qf < 4; ++qf) {
        float iz[4];
#pragma unroll
        for (int r = 0; r < 4; ++r)
            iz[r] = 1.f / (zl[qf][0][l4 * 4 + r] + zl[qf][1][l4 * 4 + r]);
#pragma unroll
        for (int cf = 0; cf < 4; ++cf) {
            int c = w * 64 + cf * 16 + l15;
            float mu = cstat[((size_t)b * 512 + c) * 2];
            float rstd = cstat[((size_t)b * 512 + c) * 2 + 1];
            const float* cp = content + ((size_t)b * 512 + c) * 4096 + n0 + qf * 16 + l4 * 4;
            float* op = out + ((size_t)b * 512 + c) * 4096 + n0 + qf * 16 + l4 * 4;
            float4 cv = *(const float4*)cp;
            float4 ov;
#pragma unroll
            for (int r = 0; r < 4; ++r) {
                float mean = pv[qf * 8 + cf][r] * iz[r];
                float sec = pv[qf * 8 + cf + 4][r] * iz[r];
                float stdv = sqrtf(fmaxf(sec - mean * mean, 0.f));
                (&ov.x)[r] = stdv * ((&cv.x)[r] - mu) * rstd + mean;
            }
            *(float4*)op = ov;
        }
    }
#undef STAGE
#undef QK
}

extern "C" void kernel_launch(void* const* d_in, const int* in_sizes, int n_in,
                              void* d_out, int out_size, void* d_ws, size_t ws_size,
                              hipStream_t stream) {
    (void)in_sizes; (void)n_in; (void)out_size; (void)ws_size;
    const float* content = (const float*)d_in[0];
    const float* style   = (const float*)d_in[1];
    const float* ckey    = (const float*)d_in[2];
    const float* skey    = (const float*)d_in[3];
    const float* f_w = (const float*)d_in[4];
    const float* f_b = (const float*)d_in[5];
    const float* g_w = (const float*)d_in[6];
    const float* g_b = (const float*)d_in[7];
    const float* h_w = (const float*)d_in[8];
    const float* h_b = (const float*)d_in[9];
    const float* wmix = (const float*)d_in[10];
    float* out = (float*)d_out;

    // Workspace layout (82 MB). Hb aliases ckT+skT (both dead by convH time;
    // same-stream kernels serialize).
    char* ws = (char*)d_ws;
    u16* ckT = (u16*)(ws + 0);                      // 16 MB  bf16 [b][n][512]
    u16* skT = (u16*)(ws + (size_t)16 * 1048576);   // 16 MB
    u16* stT = (u16*)(ws + (size_t)32 * 1048576);   // 16 MB
    u16* fwB = (u16*)(ws + (size_t)48 * 1048576);   // 512 KB
    u16* gwB = (u16*)(ws + (size_t)48 * 1048576 + 524288);
    u16* hwB = (u16*)(ws + (size_t)48 * 1048576 + 1048576);
    float* cst = (float*)(ws + (size_t)48 * 1048576 + 1572864);  // 16 KB
    u16* Qb  = (u16*)(ws + (size_t)50 * 1048576);   // 16 MB  Fm pixel-major
    u16* Gb  = (u16*)(ws + (size_t)66 * 1048576);   // 16 MB  Gm pixel-major
    u16* Hb  = (u16*)(ws + 0);                      // 32 MB  [Hm;Hm^2] channel-major

    k_cast<<<256, 256, 0, stream>>>(f_w, fwB, 65536);
    k_cast<<<256, 256, 0, stream>>>(g_w, gwB, 65536);
    k_cast<<<256, 256, 0, stream>>>(h_w, hwB, 65536);
    k_transpose<<<dim3(64, 8, 4), 256, 0, stream>>>(ckey, ckT);
    k_transpose<<<dim3(64, 8, 4), 256, 0, stream>>>(skey, skT);
    k_transpose<<<dim3(64, 8, 4), 256, 0, stream>>>(style, stT);
    k_cstats<<<dim3(512, 4), 256, 0, stream>>>(content, cst);
    k_convP<<<dim3(64, 8, 4), 256, 0, stream>>>(ckT, fwB, f_b, Qb);
    k_convP<<<dim3(64, 8, 4), 256, 0, stream>>>(skT, gwB, g_b, Gb);
    k_convH<<<dim3(8, 64, 4), 256, 0, stream>>>(stT, hwB, h_b, Hb);
    k_attn<<<dim3(256), 512, 0, stream>>>(Qb, Gb, Hb, wmix, content, cst, out);
}

// Round 5
// 819.981 us; speedup vs baseline: 3.1063x; 1.4478x over previous
//
#include <hip/hip_runtime.h>
#include <hip/hip_bf16.h>
#include <hip/hip_fp16.h>
#include <stdint.h>

typedef float f32x4 __attribute__((ext_vector_type(4)));
typedef short short8 __attribute__((ext_vector_type(8)));
typedef unsigned short u16;

static __device__ __forceinline__ u16 f2bf(float f) {
    __hip_bfloat16 h = __float2bfloat16(f);
    return *reinterpret_cast<const u16*>(&h);
}
static __device__ __forceinline__ u16 f2h(float f) {
    __half h = __float2half(f);
    return *reinterpret_cast<const u16*>(&h);
}
static __device__ __forceinline__ float h2f(u16 b) {
    __half h = *reinterpret_cast<const __half*>(&b);
    return __half2float(h);
}

// async global->LDS, 16B per lane: LDS dest = wave-uniform base + lane*16,
// global src is per-lane (carries the swizzle).
static __device__ __forceinline__ void gload16(const void* g, void* l) {
    __builtin_amdgcn_global_load_lds((const __attribute__((address_space(1))) void*)g,
                                     (__attribute__((address_space(3))) void*)l, 16, 0, 0);
}

// ---------------- weights f32 -> bf16 cast, 3 arrays in one launch ----------------
__global__ void k_cast3(const float* __restrict__ a, const float* __restrict__ b,
                        const float* __restrict__ c, u16* __restrict__ oa,
                        u16* __restrict__ ob, u16* __restrict__ oc) {
    int i = blockIdx.x * blockDim.x + threadIdx.x;   // 3*65536 float4-groups
    int which = i >> 16, j = i & 65535;
    const float* in = (which == 0) ? a : (which == 1) ? b : c;
    u16* out = (which == 0) ? oa : (which == 1) ? ob : oc;
    float4 v = ((const float4*)in)[j];
    ushort4 o;
    o.x = f2bf(v.x); o.y = f2bf(v.y); o.z = f2bf(v.z); o.w = f2bf(v.w);
    ((ushort4*)out)[j] = o;
}

// ------------- transpose+cast: f32 [b][512][4096] -> bf16 [b][4096][512] -------------
__global__ __launch_bounds__(256) void k_transpose(const float* __restrict__ in, u16* __restrict__ out) {
    __shared__ float t[64][65];
    int b = blockIdx.z;
    int c0 = blockIdx.y * 64;
    int n0 = blockIdx.x * 64;
    const float* ip = in + ((size_t)b * 512 + c0) * 4096 + n0;
#pragma unroll
    for (int i = 0; i < 16; ++i) {
        int idx = threadIdx.x + i * 256;
        int cl = idx >> 6, nl = idx & 63;
        t[cl][nl] = ip[(size_t)cl * 4096 + nl];
    }
    __syncthreads();
    u16* op = out + ((size_t)b * 4096 + n0) * 512 + c0;
#pragma unroll
    for (int i = 0; i < 16; ++i) {
        int idx = threadIdx.x + i * 256;
        int nr = idx >> 6, cc = idx & 63;
        op[(size_t)nr * 512 + cc] = f2bf(t[cc][nr]);
    }
}

// ------------- content per-(b,c) mean / rstd (ddof=1, +eps) -------------
__global__ __launch_bounds__(256) void k_cstats(const float* __restrict__ content, float* __restrict__ cstat) {
    int c = blockIdx.x, b = blockIdx.y;
    const float4* r4 = (const float4*)(content + ((size_t)b * 512 + c) * 4096);
    float s = 0.f, ss = 0.f;
    for (int i = threadIdx.x; i < 1024; i += 256) {
        float4 v = r4[i];
        s += v.x + v.y + v.z + v.w;
        ss += v.x * v.x + v.y * v.y + v.z * v.z + v.w * v.w;
    }
#pragma unroll
    for (int k = 1; k < 64; k <<= 1) { s += __shfl_xor(s, k); ss += __shfl_xor(ss, k); }
    __shared__ float ls[4], lss[4];
    int w = threadIdx.x >> 6;
    if ((threadIdx.x & 63) == 0) { ls[w] = s; lss[w] = ss; }
    __syncthreads();
    if (threadIdx.x == 0) {
        s = ls[0] + ls[1] + ls[2] + ls[3];
        ss = lss[0] + lss[1] + lss[2] + lss[3];
        float mu = s / 4096.f;
        float var = (ss - 4096.f * mu * mu) / 4095.f;
        cstat[((size_t)b * 512 + c) * 2] = mu;
        cstat[((size_t)b * 512 + c) * 2 + 1] = rsqrtf(var + 1e-5f);
    }
}

// ------------- conv1x1, pixel-major output -------------
__global__ __launch_bounds__(256) void k_convP(const u16* __restrict__ XT, const u16* __restrict__ Wb,
                                               const float* __restrict__ bias, u16* __restrict__ out) {
    int b = blockIdx.z;
    int n0 = blockIdx.x * 64, o0 = blockIdx.y * 64;
    int lane = threadIdx.x & 63, w = threadIdx.x >> 6;
    int l15 = lane & 15, l4 = lane >> 4;
    const u16* ap = XT + ((size_t)b * 4096 + n0 + w * 16 + l15) * 512 + l4 * 8;
    f32x4 acc[4] = {{0,0,0,0},{0,0,0,0},{0,0,0,0},{0,0,0,0}};
#pragma unroll
    for (int kk = 0; kk < 16; ++kk) {
        short8 a = *(const short8*)(ap + kk * 32);
#pragma unroll
        for (int bo = 0; bo < 4; ++bo) {
            const u16* bp = Wb + ((size_t)(o0 + bo * 16 + l15)) * 512 + kk * 32 + l4 * 8;
            short8 bb = *(const short8*)bp;
            acc[bo] = __builtin_amdgcn_mfma_f32_16x16x32_bf16(a, bb, acc[bo], 0, 0, 0);
        }
    }
#pragma unroll
    for (int bo = 0; bo < 4; ++bo) {
        float bv = bias[o0 + bo * 16 + l15];
#pragma unroll
        for (int r = 0; r < 4; ++r) {
            int n = n0 + w * 16 + l4 * 4 + r;
            out[((size_t)b * 4096 + n) * 512 + o0 + bo * 16 + l15] = f2bf(acc[bo][r] + bv);
        }
    }
}

// ------------- conv1x1, channel-major output + squares -------------
__global__ __launch_bounds__(256) void k_convH(const u16* __restrict__ ST, const u16* __restrict__ Wb,
                                               const float* __restrict__ bias, u16* __restrict__ out) {
    int b = blockIdx.z;
    int o0 = blockIdx.x * 64, m0 = blockIdx.y * 64;
    int lane = threadIdx.x & 63, w = threadIdx.x >> 6;
    int l15 = lane & 15, l4 = lane >> 4;
    const u16* ap = Wb + ((size_t)(o0 + w * 16 + l15)) * 512 + l4 * 8;
    f32x4 acc[4] = {{0,0,0,0},{0,0,0,0},{0,0,0,0},{0,0,0,0}};
#pragma unroll
    for (int kk = 0; kk < 16; ++kk) {
        short8 a = *(const short8*)(ap + kk * 32);
#pragma unroll
        for (int mb = 0; mb < 4; ++mb) {
            const u16* bp = ST + ((size_t)b * 4096 + m0 + mb * 16 + l15) * 512 + kk * 32 + l4 * 8;
            short8 bb = *(const short8*)bp;
            acc[mb] = __builtin_amdgcn_mfma_f32_16x16x32_bf16(a, bb, acc[mb], 0, 0, 0);
        }
    }
#pragma unroll
    for (int r = 0; r < 4; ++r) {
        int o = o0 + w * 16 + l4 * 4 + r;
        float bv = bias[o];
#pragma unroll
        for (int mb = 0; mb < 4; ++mb) {
            float v = acc[mb][r] + bv;
            size_t base = ((size_t)b * 1024 + o) * 4096 + m0 + mb * 16 + l15;
            out[base] = f2bf(v);
            out[base + (size_t)512 * 4096] = f2bf(v * v);
        }
    }
}

// ============ split path, kernel A: QK + online softmax stats + fp16 logits ============
// grid 512: b=(bid&7)>>1 (XCD-pair/batch); g=bid>>3; qt=(bid&1)*32+(g>>1); half=g&1
// 8 waves: R=w>>1 (16 q-rows), MB=w&1 (16 of 32 kv-cols). mc: 64 steps of 32 kv.
__global__ __launch_bounds__(512, 4) void k_attnA(
    const u16* __restrict__ Q, const u16* __restrict__ G,
    u16* __restrict__ Lg, float* __restrict__ stats) {

    __shared__ __align__(16) u16 gtile[2][32 * 512];   // 2 x 32KB
    __shared__ float smd[4][2][16], ssd_[4][2][16], smsp[4][2][16], sssp[4][2][16];

    int bid = blockIdx.x;
    int b = (bid & 7) >> 1;
    int g = bid >> 3;
    int qt = ((bid & 1) << 5) | (g >> 1);
    int half = g & 1;
    int n0 = qt * 64;
    int kv0 = half * 2048;
    int lane = threadIdx.x & 63, w = threadIdx.x >> 6;
    int l15 = lane & 15, l4 = lane >> 4;
    int R = w >> 1, MB = w & 1;

    const u16* qp = Q + ((size_t)b * 4096 + n0 + R * 16 + l15) * 512 + l4 * 8;
    short8 q[16];
#pragma unroll
    for (int kk = 0; kk < 16; ++kk) q[kk] = *(const short8*)(qp + kk * 32);

    const char* gbat = (const char*)(G + (size_t)b * 4096 * 512);

#define STAGEA(buf, mc)                                                                \
    {                                                                                  \
        _Pragma("unroll")                                                              \
        for (int j = 0; j < 4; ++j) {                                                  \
            int row = j * 8 + w;                                                       \
            const char* src = gbat + ((size_t)(kv0 + (mc) * 32 + row)) * 1024          \
                              + ((lane * 16) ^ ((row & 7) << 4));                      \
            gload16(src, (char*)&gtile[buf][0] + row * 1024);                          \
        }                                                                              \
    }

    float md[4], sd[4], ms[4], ss[4];
#pragma unroll
    for (int r = 0; r < 4; ++r) { md[r] = -1e30f; sd[r] = 0.f; ms[r] = -1e30f; ss[r] = 0.f; }

    STAGEA(0, 0);
    __syncthreads();
    for (int mc = 0; mc < 64; ++mc) {
        int buf = mc & 1;
        if (mc < 63) STAGEA(buf ^ 1, mc + 1);
        f32x4 acc = {0, 0, 0, 0};
        const char* gt = (const char*)&gtile[buf][0];
#pragma unroll
        for (int kk = 0; kk < 16; ++kk) {
            int row = MB * 16 + l15;
            int y = (kk * 64 + l4 * 16) ^ ((row & 7) << 4);
            short8 gg = *(const short8*)(gt + row * 1024 + y);
            acc = __builtin_amdgcn_mfma_f32_16x16x32_bf16(q[kk], gg, acc, 0, 0, 0);
        }
#pragma unroll
        for (int r = 0; r < 4; ++r) {
            float v = acc[r];
            float mn = fmaxf(md[r], v);
            sd[r] = sd[r] * __expf(md[r] - mn) + __expf(v - mn);
            md[r] = mn;
            float vs = fmaxf(v, 0.f);
            mn = fmaxf(ms[r], vs);
            ss[r] = ss[r] * __expf(ms[r] - mn) + __expf(vs - mn);
            ms[r] = mn;
            int qg = n0 + R * 16 + l4 * 4 + r;
            Lg[((size_t)b * 4096 + qg) * 4096 + kv0 + mc * 32 + MB * 16 + l15] = f2h(v);
        }
        __syncthreads();
    }

    // 16-lane merge per row-group
#pragma unroll
    for (int r = 0; r < 4; ++r) {
#pragma unroll
        for (int k = 1; k < 16; k <<= 1) {
            float mo = __shfl_xor(md[r], k), so = __shfl_xor(sd[r], k);
            float mn = fmaxf(md[r], mo);
            sd[r] = sd[r] * __expf(md[r] - mn) + so * __expf(mo - mn);
            md[r] = mn;
            mo = __shfl_xor(ms[r], k); so = __shfl_xor(ss[r], k);
            mn = fmaxf(ms[r], mo);
            ss[r] = ss[r] * __expf(ms[r] - mn) + so * __expf(mo - mn);
            ms[r] = mn;
        }
    }
    if (l15 == 0) {
#pragma unroll
        for (int r = 0; r < 4; ++r) {
            int row = l4 * 4 + r;
            smd[R][MB][row] = md[r]; ssd_[R][MB][row] = sd[r];
            smsp[R][MB][row] = ms[r]; sssp[R][MB][row] = ss[r];
        }
    }
    __syncthreads();
    if (MB == 0 && l15 == 0) {
#pragma unroll
        for (int r = 0; r < 4; ++r) {
            int row = l4 * 4 + r;
            float m0_ = smd[R][0][row], s0_ = ssd_[R][0][row];
            float m1_ = smd[R][1][row], s1_ = ssd_[R][1][row];
            float mn = fmaxf(m0_, m1_);
            float Sd = s0_ * __expf(m0_ - mn) + s1_ * __expf(m1_ - mn);
            float Md = mn;
            m0_ = smsp[R][0][row]; s0_ = sssp[R][0][row];
            m1_ = smsp[R][1][row]; s1_ = sssp[R][1][row];
            mn = fmaxf(m0_, m1_);
            float Ss = s0_ * __expf(m0_ - mn) + s1_ * __expf(m1_ - mn);
            float Ms = mn;
            int qg = n0 + R * 16 + l4 * 4 + r;
            float4 st = {Md, Sd, Ms, Ss};
            *(float4*)(stats + (((size_t)b * 4096 + qg) * 2 + half) * 4) = st;
        }
    }
#undef STAGEA
}

// ============ split path, kernel B: e = exp(mix of softmaxes) + PV + epilogue ============
// grid 256: b=(bid&7)>>1, qt=(bid&1)*32+(bid>>3). 8 waves.
// producer: lane owns (q-row = w*8+(lane>>3), kv-octet = (lane&7)*8) -> bf16 e-tile (dbuf)
// consumer: wave w owns 64 mean-channels (w*64..) + matching 64 sec-channels (+512)
__global__ __launch_bounds__(512, 2) void k_attnB(
    const u16* __restrict__ Lg, const u16* __restrict__ H,
    const float* __restrict__ stats, const float* __restrict__ wmix,
    const float* __restrict__ content, const float* __restrict__ cstat,
    float* __restrict__ out) {

    __shared__ __align__(16) u16 et[2][4096];   // 2 x 8KB bf16 e-tile [64q][64kv]
    __shared__ float zrow[64];

    int bid = blockIdx.x;
    int b = (bid & 7) >> 1;
    int qt = ((bid & 1) << 5) | (bid >> 3);
    int n0 = qt * 64;
    int lane = threadIdx.x & 63, w = threadIdx.x >> 6;
    int l15 = lane & 15, l4 = lane >> 4;

    float wa = wmix[0], wbv = wmix[1];
    float wmx = fmaxf(wa, wbv);
    float e0 = __expf(wa - wmx), e1 = __expf(wbv - wmx);
    float w0 = e0 / (e0 + e1), w1 = e1 / (e0 + e1);

    // producer identity + merged stats (kv-halves)
    int qlocal = w * 8 + (lane >> 3);
    int kvl = (lane & 7) * 8;
    float md, isd, ms, iss;
    {
        const float* sp = stats + (((size_t)b * 4096 + n0 + qlocal) * 2) * 4;
        float4 s0 = *(const float4*)sp;
        float4 s1 = *(const float4*)(sp + 4);
        float mn = fmaxf(s0.x, s1.x);
        float S = s0.y * __expf(s0.x - mn) + s1.y * __expf(s1.x - mn);
        md = mn; isd = 1.f / S;
        mn = fmaxf(s0.z, s1.z);
        S = s0.w * __expf(s0.z - mn) + s1.w * __expf(s1.z - mn);
        ms = mn; iss = 1.f / S;
    }
    const u16* lgrow = Lg + ((size_t)b * 4096 + n0 + qlocal) * 4096 + kvl;
    unsigned ewbyte = (unsigned)(qlocal * 128) + (((unsigned)(lane & 7) * 16) ^ ((unsigned)(qlocal & 7) << 4));

    float z = 0.f;

#define PRODUCE(buf, mc)                                                               \
    {                                                                                  \
        short8 L8 = *(const short8*)(lgrow + (size_t)(mc) * 64);                       \
        short8 ebf;                                                                    \
        _Pragma("unroll")                                                              \
        for (int j = 0; j < 8; ++j) {                                                  \
            float v = h2f((u16)L8[j]);                                                 \
            float ed = __expf(v - md) * isd;                                           \
            float es = __expf(fmaxf(v, 0.f) - ms) * iss;                               \
            float e = __expf(w0 * ed + w1 * es);                                       \
            z += e;                                                                    \
            ebf[j] = (short)f2bf(e);                                                   \
        }                                                                              \
        *(short8*)((char*)&et[buf][0] + ewbyte) = ebf;                                 \
    }

    f32x4 pv[32];
#pragma unroll
    for (int i = 0; i < 32; ++i) pv[i] = (f32x4){0, 0, 0, 0};

    PRODUCE(0, 0);
    __syncthreads();
    for (int mc = 0; mc < 64; ++mc) {
        int buf = mc & 1;
        if (mc < 63) PRODUCE(buf ^ 1, mc + 1);
        const char* eb = (const char*)&et[buf][0];
        const u16* hb = H + (size_t)b * 1024 * 4096 + (size_t)mc * 64 + l4 * 8;
#pragma unroll
        for (int ks = 0; ks < 2; ++ks) {
            short8 af[4];
#pragma unroll
            for (int qf = 0; qf < 4; ++qf) {
                int qq = qf * 16 + l15;
                int y = (ks * 64 + l4 * 16) ^ ((qq & 7) << 4);
                af[qf] = *(const short8*)(eb + qq * 128 + y);
            }
#pragma unroll
            for (int cf = 0; cf < 8; ++cf) {
                int c = (cf < 4) ? (w * 64 + cf * 16 + l15) : (512 + w * 64 + (cf - 4) * 16 + l15);
                short8 hh = *(const short8*)(hb + (size_t)c * 4096 + ks * 32);
#pragma unroll
                for (int qf = 0; qf < 4; ++qf)
                    pv[qf * 8 + cf] = __builtin_amdgcn_mfma_f32_16x16x32_bf16(af[qf], hh, pv[qf * 8 + cf], 0, 0, 0);
            }
        }
        __syncthreads();
    }

    // Z: reduce the 8 kv-octet lanes of each q-row (contiguous 8 lanes)
    z += __shfl_xor(z, 1);
    z += __shfl_xor(z, 2);
    z += __shfl_xor(z, 4);
    if ((lane & 7) == 0) zrow[qlocal] = z;
    __syncthreads();

    // epilogue: mean/std + fused mean_variance_norm(content), float4 I/O
#pragma unroll
    for (int qf = 0; qf < 4; ++qf) {
        float iz[4];
#pragma unroll
        for (int r = 0; r < 4; ++r)
            iz[r] = 1.f / zrow[qf * 16 + l4 * 4 + r];
#pragma unroll
        for (int cf = 0; cf < 4; ++cf) {
            int c = w * 64 + cf * 16 + l15;
            float mu = cstat[((size_t)b * 512 + c) * 2];
            float rstd = cstat[((size_t)b * 512 + c) * 2 + 1];
            const float* cp = content + ((size_t)b * 512 + c) * 4096 + n0 + qf * 16 + l4 * 4;
            float* op = out + ((size_t)b * 512 + c) * 4096 + n0 + qf * 16 + l4 * 4;
            float4 cv = *(const float4*)cp;
            float4 ov;
#pragma unroll
            for (int r = 0; r < 4; ++r) {
                float mean = pv[qf * 8 + cf][r] * iz[r];
                float sec = pv[qf * 8 + cf + 4][r] * iz[r];
                float stdv = sqrtf(fmaxf(sec - mean * mean, 0.f));
                (&ov.x)[r] = stdv * ((&cv.x)[r] - mu) * rstd + mean;
            }
            *(float4*)op = ov;
        }
    }
#undef PRODUCE
}

// ============ fallback: round-4 fused kernel (used when ws too small for logits) ============
__global__ __launch_bounds__(512, 2) void k_attn(
    const u16* __restrict__ Q, const u16* __restrict__ G, const u16* __restrict__ H,
    const float* __restrict__ wmix, const float* __restrict__ content,
    const float* __restrict__ cstat, float* __restrict__ out) {

    __shared__ __align__(16) u16 gtile[2][64 * 512];
    __shared__ __align__(16) u16 etile[64 * 64];
    __shared__ float smd[4][2][16], ssd_[4][2][16], smsp[4][2][16], sssp[4][2][16];
    __shared__ float zl[4][2][16];

    int bid = blockIdx.x;
    int b = (bid & 7) >> 1;
    int qt = ((bid & 1) << 5) | (bid >> 3);
    int n0 = qt * 64;
    int tid = threadIdx.x;
    int lane = tid & 63, w = tid >> 6;
    int l15 = lane & 15, l4 = lane >> 4;
    int R = w >> 1, MB = w & 1;

    float wa = wmix[0], wbv = wmix[1];
    float wmx = fmaxf(wa, wbv);
    float e0 = __expf(wa - wmx), e1 = __expf(wbv - wmx);
    float w0 = e0 / (e0 + e1), w1 = e1 / (e0 + e1);

    const u16* qp = Q + ((size_t)b * 4096 + n0 + R * 16 + l15) * 512 + l4 * 8;
    short8 q[16];
#pragma unroll
    for (int kk = 0; kk < 16; ++kk) q[kk] = *(const short8*)(qp + kk * 32);

    const char* gbat = (const char*)(G + (size_t)b * 4096 * 512);

#define STAGE(buf, mc)                                                                 \
    {                                                                                  \
        _Pragma("unroll")                                                              \
        for (int j = 0; j < 8; ++j) {                                                  \
            int row = j * 8 + w;                                                       \
            const char* src = gbat + ((size_t)((mc) * 64 + row)) * 1024                \
                              + ((lane * 16) ^ ((row & 7) << 4));                      \
            gload16(src, (char*)&gtile[buf][0] + row * 1024);                          \
        }                                                                              \
    }
#define QK(buf, acc)                                                                   \
    {                                                                                  \
        const char* gt = (const char*)&gtile[buf][0];                                  \
        _Pragma("unroll")                                                              \
        for (int kk = 0; kk < 16; ++kk) {                                              \
            _Pragma("unroll")                                                          \
            for (int t = 0; t < 2; ++t) {                                              \
                int row = MB * 32 + t * 16 + l15;                                      \
                int y = (kk * 64 + l4 * 16) ^ ((row & 7) << 4);                        \
                short8 gg = *(const short8*)(gt + row * 1024 + y);                     \
                acc[t] = __builtin_amdgcn_mfma_f32_16x16x32_bf16(q[kk], gg, acc[t], 0, 0, 0); \
            }                                                                          \
        }                                                                              \
    }

    float md[4], sd[4], ms[4], ss[4];
#pragma unroll
    for (int r = 0; r < 4; ++r) { md[r] = -1e30f; sd[r] = 0.f; ms[r] = -1e30f; ss[r] = 0.f; }

    STAGE(0, 0);
    __syncthreads();
    for (int mc = 0; mc < 64; ++mc) {
        int buf = mc & 1;
        if (mc < 63) STAGE(buf ^ 1, mc + 1);
        f32x4 acc[2] = {{0,0,0,0},{0,0,0,0}};
        QK(buf, acc);
#pragma unroll
        for (int t = 0; t < 2; ++t)
#pragma unroll
            for (int r = 0; r < 4; ++r) {
                float v = acc[t][r];
                float mn = fmaxf(md[r], v);
                sd[r] = sd[r] * __expf(md[r] - mn) + __expf(v - mn);
                md[r] = mn;
                float vs = fmaxf(v, 0.f);
                mn = fmaxf(ms[r], vs);
                ss[r] = ss[r] * __expf(ms[r] - mn) + __expf(vs - mn);
                ms[r] = mn;
            }
        __syncthreads();
    }

#pragma unroll
    for (int r = 0; r < 4; ++r) {
#pragma unroll
        for (int k = 1; k < 16; k <<= 1) {
            float mo = __shfl_xor(md[r], k), so = __shfl_xor(sd[r], k);
            float mn = fmaxf(md[r], mo);
            sd[r] = sd[r] * __expf(md[r] - mn) + so * __expf(mo - mn);
            md[r] = mn;
            mo = __shfl_xor(ms[r], k); so = __shfl_xor(ss[r], k);
            mn = fmaxf(ms[r], mo);
            ss[r] = ss[r] * __expf(ms[r] - mn) + so * __expf(mo - mn);
            ms[r] = mn;
        }
    }
    if (l15 == 0) {
#pragma unroll
        for (int r = 0; r < 4; ++r) {
            int row = l4 * 4 + r;
            smd[R][MB][row] = md[r]; ssd_[R][MB][row] = sd[r];
            smsp[R][MB][row] = ms[r]; sssp[R][MB][row] = ss[r];
        }
    }
    __syncthreads();
    float isd[4], iss[4];
#pragma unroll
    for (int r = 0; r < 4; ++r) {
        int row = l4 * 4 + r;
        float m0_ = smd[R][0][row], s0_ = ssd_[R][0][row];
        float m1_ = smd[R][1][row], s1_ = ssd_[R][1][row];
        float mn = fmaxf(m0_, m1_);
        isd[r] = 1.f / (s0_ * __expf(m0_ - mn) + s1_ * __expf(m1_ - mn));
        md[r] = mn;
        m0_ = smsp[R][0][row]; s0_ = sssp[R][0][row];
        m1_ = smsp[R][1][row]; s1_ = sssp[R][1][row];
        mn = fmaxf(m0_, m1_);
        iss[r] = 1.f / (s0_ * __expf(m0_ - mn) + s1_ * __expf(m1_ - mn));
        ms[r] = mn;
    }

    f32x4 pv[32];
#pragma unroll
    for (int i = 0; i < 32; ++i) pv[i] = (f32x4){0, 0, 0, 0};
    float Z[4] = {0, 0, 0, 0};

    STAGE(0, 0);
    __syncthreads();
    for (int mc = 0; mc < 64; ++mc) {
        int buf = mc & 1;
        if (mc < 63) STAGE(buf ^ 1, mc + 1);
        f32x4 acc[2] = {{0,0,0,0},{0,0,0,0}};
        QK(buf, acc);
        char* eb = (char*)&etile[0];
#pragma unroll
        for (int t = 0; t < 2; ++t)
#pragma unroll
            for (int r = 0; r < 4; ++r) {
                float v = acc[t][r];
                float ed = __expf(v - md[r]) * isd[r];
                float es = __expf(fmaxf(v, 0.f) - ms[r]) * iss[r];
                float e = __expf(w0 * ed + w1 * es);
                Z[r] += e;
                int row = R * 16 + l4 * 4 + r;
                int y = ((MB * 32 + t * 16 + l15) * 2) ^ ((row & 7) << 4);
                *(u16*)(eb + row * 128 + y) = f2bf(e);
            }
        asm volatile("s_waitcnt lgkmcnt(0)" ::: "memory");
        __builtin_amdgcn_s_barrier();
        __builtin_amdgcn_sched_barrier(0);

        const u16* hb = H + (size_t)b * 1024 * 4096 + (size_t)mc * 64 + l4 * 8;
#pragma unroll
        for (int ks = 0; ks < 2; ++ks) {
            short8 af[4];
#pragma unroll
            for (int qf = 0; qf < 4; ++qf) {
                int rowA = qf * 16 + l15;
                int y = (ks * 64 + l4 * 16) ^ ((rowA & 7) << 4);
                af[qf] = *(const short8*)(eb + rowA * 128 + y);
            }
#pragma unroll
            for (int cf = 0; cf < 8; ++cf) {
                int c = (cf < 4) ? (w * 64 + cf * 16 + l15) : (512 + w * 64 + (cf - 4) * 16 + l15);
                short8 hh = *(const short8*)(hb + (size_t)c * 4096 + ks * 32);
#pragma unroll
                for (int qf = 0; qf < 4; ++qf)
                    pv[qf * 8 + cf] = __builtin_amdgcn_mfma_f32_16x16x32_bf16(af[qf], hh, pv[qf * 8 + cf], 0, 0, 0);
            }
        }
        __syncthreads();
    }

#pragma unroll
    for (int r = 0; r < 4; ++r)
#pragma unroll
        for (int k = 1; k < 16; k <<= 1) Z[r] += __shfl_xor(Z[r], k);
    if (l15 == 0) {
#pragma unroll
        for (int r = 0; r < 4; ++r) zl[R][MB][l4 * 4 + r] = Z[r];
    }
    __syncthreads();

#pragma unroll
    for (int qf = 0; qf < 4; ++qf) {
        float iz[4];
#pragma unroll
        for (int r = 0; r < 4; ++r)
            iz[r] = 1.f / (zl[qf][0][l4 * 4 + r] + zl[qf][1][l4 * 4 + r]);
#pragma unroll
        for (int cf = 0; cf < 4; ++cf) {
            int c = w * 64 + cf * 16 + l15;
            float mu = cstat[((size_t)b * 512 + c) * 2];
            float rstd = cstat[((size_t)b * 512 + c) * 2 + 1];
            const float* cp = content + ((size_t)b * 512 + c) * 4096 + n0 + qf * 16 + l4 * 4;
            float* op = out + ((size_t)b * 512 + c) * 4096 + n0 + qf * 16 + l4 * 4;
            float4 cv = *(const float4*)cp;
            float4 ov;
#pragma unroll
            for (int r = 0; r < 4; ++r) {
                float mean = pv[qf * 8 + cf][r] * iz[r];
                float sec = pv[qf * 8 + cf + 4][r] * iz[r];
                float stdv = sqrtf(fmaxf(sec - mean * mean, 0.f));
                (&ov.x)[r] = stdv * ((&cv.x)[r] - mu) * rstd + mean;
            }
            *(float4*)op = ov;
        }
    }
#undef STAGE
#undef QK
}

extern "C" void kernel_launch(void* const* d_in, const int* in_sizes, int n_in,
                              void* d_out, int out_size, void* d_ws, size_t ws_size,
                              hipStream_t stream) {
    (void)in_sizes; (void)n_in; (void)out_size;
    const float* content = (const float*)d_in[0];
    const float* style   = (const float*)d_in[1];
    const float* ckey    = (const float*)d_in[2];
    const float* skey    = (const float*)d_in[3];
    const float* f_w = (const float*)d_in[4];
    const float* f_b = (const float*)d_in[5];
    const float* g_w = (const float*)d_in[6];
    const float* g_b = (const float*)d_in[7];
    const float* h_w = (const float*)d_in[8];
    const float* h_b = (const float*)d_in[9];
    const float* wmix = (const float*)d_in[10];
    float* out = (float*)d_out;

    const size_t MiB = 1048576;
    char* ws = (char*)d_ws;
    // Common prep layout. Hb aliases ckT+skT (dead by convH time; same-stream serialization).
    u16* ckT = (u16*)(ws + 0);
    u16* skT = (u16*)(ws + 16 * MiB);
    u16* stT = (u16*)(ws + 32 * MiB);
    u16* fwB = (u16*)(ws + 48 * MiB);
    u16* gwB = (u16*)(ws + 48 * MiB + 524288);
    u16* hwB = (u16*)(ws + 49 * MiB);
    float* cst = (float*)(ws + 49 * MiB + 524288);   // 16 KB
    u16* Qb  = (u16*)(ws + 50 * MiB);
    u16* Gb  = (u16*)(ws + 66 * MiB);
    u16* Hb  = (u16*)(ws + 0);
    // Split-path extras: fp16 logits [4][4096][4096] (128 MiB) + stats (512 KB)
    u16* Lg  = (u16*)(ws + 82 * MiB);
    float* stats = (float*)(ws + 210 * MiB);
    const size_t NEED = 210 * MiB + 524288 + 65536;
    bool split = (ws_size >= NEED);

    k_cast3<<<768, 256, 0, stream>>>(f_w, g_w, h_w, fwB, gwB, hwB);
    k_transpose<<<dim3(64, 8, 4), 256, 0, stream>>>(ckey, ckT);
    k_transpose<<<dim3(64, 8, 4), 256, 0, stream>>>(skey, skT);
    k_transpose<<<dim3(64, 8, 4), 256, 0, stream>>>(style, stT);
    k_cstats<<<dim3(512, 4), 256, 0, stream>>>(content, cst);
    k_convP<<<dim3(64, 8, 4), 256, 0, stream>>>(ckT, fwB, f_b, Qb);
    k_convP<<<dim3(64, 8, 4), 256, 0, stream>>>(skT, gwB, g_b, Gb);
    k_convH<<<dim3(8, 64, 4), 256, 0, stream>>>(stT, hwB, h_b, Hb);
    if (split) {
        k_attnA<<<dim3(512), 512, 0, stream>>>(Qb, Gb, Lg, stats);
        k_attnB<<<dim3(256), 512, 0, stream>>>(Lg, Hb, stats, wmix, content, cst, out);
    } else {
        k_attn<<<dim3(256), 512, 0, stream>>>(Qb, Gb, Hb, wmix, content, cst, out);
    }
}

// Round 6
// 784.875 us; speedup vs baseline: 3.2452x; 1.0447x over previous
//
#include <hip/hip_runtime.h>
#include <hip/hip_bf16.h>
#include <hip/hip_fp16.h>
#include <stdint.h>

typedef float f32x4 __attribute__((ext_vector_type(4)));
typedef short short8 __attribute__((ext_vector_type(8)));
typedef unsigned short u16;

static __device__ __forceinline__ u16 f2bf(float f) {
    __hip_bfloat16 h = __float2bfloat16(f);
    return *reinterpret_cast<const u16*>(&h);
}
static __device__ __forceinline__ u16 f2h(float f) {
    __half h = __float2half(f);
    return *reinterpret_cast<const u16*>(&h);
}
static __device__ __forceinline__ float h2f(u16 b) {
    __half h = *reinterpret_cast<const __half*>(&b);
    return __half2float(h);
}

// async global->LDS, 16B per lane: LDS dest = wave-uniform base + lane*16,
// global src is per-lane (carries the swizzle).
static __device__ __forceinline__ void gload16(const void* g, void* l) {
    __builtin_amdgcn_global_load_lds((const __attribute__((address_space(1))) void*)g,
                                     (__attribute__((address_space(3))) void*)l, 16, 0, 0);
}

// ---------------- weights f32 -> bf16 cast, 3 arrays in one launch ----------------
__global__ void k_cast3(const float* __restrict__ a, const float* __restrict__ b,
                        const float* __restrict__ c, u16* __restrict__ oa,
                        u16* __restrict__ ob, u16* __restrict__ oc) {
    int i = blockIdx.x * blockDim.x + threadIdx.x;   // 3*65536 float4-groups
    int which = i >> 16, j = i & 65535;
    const float* in = (which == 0) ? a : (which == 1) ? b : c;
    u16* out = (which == 0) ? oa : (which == 1) ? ob : oc;
    float4 v = ((const float4*)in)[j];
    ushort4 o;
    o.x = f2bf(v.x); o.y = f2bf(v.y); o.z = f2bf(v.z); o.w = f2bf(v.w);
    ((ushort4*)out)[j] = o;
}

// ------------- transpose+cast: f32 [b][512][4096] -> bf16 [b][4096][512] -------------
__global__ __launch_bounds__(256) void k_transpose(const float* __restrict__ in, u16* __restrict__ out) {
    __shared__ float t[64][65];
    int b = blockIdx.z;
    int c0 = blockIdx.y * 64;
    int n0 = blockIdx.x * 64;
    const float* ip = in + ((size_t)b * 512 + c0) * 4096 + n0;
#pragma unroll
    for (int i = 0; i < 16; ++i) {
        int idx = threadIdx.x + i * 256;
        int cl = idx >> 6, nl = idx & 63;
        t[cl][nl] = ip[(size_t)cl * 4096 + nl];
    }
    __syncthreads();
    u16* op = out + ((size_t)b * 4096 + n0) * 512 + c0;
#pragma unroll
    for (int i = 0; i < 16; ++i) {
        int idx = threadIdx.x + i * 256;
        int nr = idx >> 6, cc = idx & 63;
        op[(size_t)nr * 512 + cc] = f2bf(t[cc][nr]);
    }
}

// ------------- content per-(b,c) mean / rstd (ddof=1, +eps) -------------
__global__ __launch_bounds__(256) void k_cstats(const float* __restrict__ content, float* __restrict__ cstat) {
    int c = blockIdx.x, b = blockIdx.y;
    const float4* r4 = (const float4*)(content + ((size_t)b * 512 + c) * 4096);
    float s = 0.f, ss = 0.f;
    for (int i = threadIdx.x; i < 1024; i += 256) {
        float4 v = r4[i];
        s += v.x + v.y + v.z + v.w;
        ss += v.x * v.x + v.y * v.y + v.z * v.z + v.w * v.w;
    }
#pragma unroll
    for (int k = 1; k < 64; k <<= 1) { s += __shfl_xor(s, k); ss += __shfl_xor(ss, k); }
    __shared__ float ls[4], lss[4];
    int w = threadIdx.x >> 6;
    if ((threadIdx.x & 63) == 0) { ls[w] = s; lss[w] = ss; }
    __syncthreads();
    if (threadIdx.x == 0) {
        s = ls[0] + ls[1] + ls[2] + ls[3];
        ss = lss[0] + lss[1] + lss[2] + lss[3];
        float mu = s / 4096.f;
        float var = (ss - 4096.f * mu * mu) / 4095.f;
        cstat[((size_t)b * 512 + c) * 2] = mu;
        cstat[((size_t)b * 512 + c) * 2 + 1] = rsqrtf(var + 1e-5f);
    }
}

// ------------- conv1x1, pixel-major output, XCD-pinned batches -------------
// grid 2048 1D: b=(bid&7)>>1 (batch per XCD pair); u=((bid&1)<<8)|(bid>>3): nt=u&63, ot=u>>6
__global__ __launch_bounds__(256) void k_convP(const u16* __restrict__ XT, const u16* __restrict__ Wb,
                                               const float* __restrict__ bias, u16* __restrict__ out) {
    int bid = blockIdx.x;
    int b = (bid & 7) >> 1;
    int u = ((bid & 1) << 8) | (bid >> 3);
    int n0 = (u & 63) * 64, o0 = (u >> 6) * 64;
    int lane = threadIdx.x & 63, w = threadIdx.x >> 6;
    int l15 = lane & 15, l4 = lane >> 4;
    const u16* ap = XT + ((size_t)b * 4096 + n0 + w * 16 + l15) * 512 + l4 * 8;
    f32x4 acc[4] = {{0,0,0,0},{0,0,0,0},{0,0,0,0},{0,0,0,0}};
#pragma unroll
    for (int kk = 0; kk < 16; ++kk) {
        short8 a = *(const short8*)(ap + kk * 32);
#pragma unroll
        for (int bo = 0; bo < 4; ++bo) {
            const u16* bp = Wb + ((size_t)(o0 + bo * 16 + l15)) * 512 + kk * 32 + l4 * 8;
            short8 bb = *(const short8*)bp;
            acc[bo] = __builtin_amdgcn_mfma_f32_16x16x32_bf16(a, bb, acc[bo], 0, 0, 0);
        }
    }
#pragma unroll
    for (int bo = 0; bo < 4; ++bo) {
        float bv = bias[o0 + bo * 16 + l15];
#pragma unroll
        for (int r = 0; r < 4; ++r) {
            int n = n0 + w * 16 + l4 * 4 + r;
            out[((size_t)b * 4096 + n) * 512 + o0 + bo * 16 + l15] = f2bf(acc[bo][r] + bv);
        }
    }
}

// ------------- conv1x1, channel-major output + squares, XCD-pinned batches -------------
// grid 2048 1D: b=(bid&7)>>1; u=((bid&1)<<8)|(bid>>3): mt=u&63, ot=u>>6
__global__ __launch_bounds__(256) void k_convH(const u16* __restrict__ ST, const u16* __restrict__ Wb,
                                               const float* __restrict__ bias, u16* __restrict__ out) {
    int bid = blockIdx.x;
    int b = (bid & 7) >> 1;
    int u = ((bid & 1) << 8) | (bid >> 3);
    int m0 = (u & 63) * 64, o0 = (u >> 6) * 64;
    int lane = threadIdx.x & 63, w = threadIdx.x >> 6;
    int l15 = lane & 15, l4 = lane >> 4;
    const u16* ap = Wb + ((size_t)(o0 + w * 16 + l15)) * 512 + l4 * 8;
    f32x4 acc[4] = {{0,0,0,0},{0,0,0,0},{0,0,0,0},{0,0,0,0}};
#pragma unroll
    for (int kk = 0; kk < 16; ++kk) {
        short8 a = *(const short8*)(ap + kk * 32);
#pragma unroll
        for (int mb = 0; mb < 4; ++mb) {
            const u16* bp = ST + ((size_t)b * 4096 + m0 + mb * 16 + l15) * 512 + kk * 32 + l4 * 8;
            short8 bb = *(const short8*)bp;
            acc[mb] = __builtin_amdgcn_mfma_f32_16x16x32_bf16(a, bb, acc[mb], 0, 0, 0);
        }
    }
#pragma unroll
    for (int r = 0; r < 4; ++r) {
        int o = o0 + w * 16 + l4 * 4 + r;
        float bv = bias[o];
#pragma unroll
        for (int mb = 0; mb < 4; ++mb) {
            float v = acc[mb][r] + bv;
            size_t base = ((size_t)b * 1024 + o) * 4096 + m0 + mb * 16 + l15;
            out[base] = f2bf(v);
            out[base + (size_t)512 * 4096] = f2bf(v * v);
        }
    }
}

// ============ kernel A: QK + online softmax stats + fp16 logits ============
// grid 512: b=(bid&7)>>1 (XCD-pair/batch); g=bid>>3; qt=(bid&1)*32+(g>>1); half=g&1
// 8 waves: R=w>>1 (16 q-rows), MB=w&1 (16 of 32 kv-cols). mc: 64 steps of 32 kv.
__global__ __launch_bounds__(512, 4) void k_attnA(
    const u16* __restrict__ Q, const u16* __restrict__ G,
    u16* __restrict__ Lg, float* __restrict__ stats) {

    __shared__ __align__(16) u16 gtile[2][32 * 512];   // 2 x 32KB
    __shared__ float smd[4][2][16], ssd_[4][2][16], smsp[4][2][16], sssp[4][2][16];

    int bid = blockIdx.x;
    int b = (bid & 7) >> 1;
    int g = bid >> 3;
    int qt = ((bid & 1) << 5) | (g >> 1);
    int half = g & 1;
    int n0 = qt * 64;
    int kv0 = half * 2048;
    int lane = threadIdx.x & 63, w = threadIdx.x >> 6;
    int l15 = lane & 15, l4 = lane >> 4;
    int R = w >> 1, MB = w & 1;

    const u16* qp = Q + ((size_t)b * 4096 + n0 + R * 16 + l15) * 512 + l4 * 8;
    short8 q[16];
#pragma unroll
    for (int kk = 0; kk < 16; ++kk) q[kk] = *(const short8*)(qp + kk * 32);

    const char* gbat = (const char*)(G + (size_t)b * 4096 * 512);

#define STAGEA(buf, mc)                                                                \
    {                                                                                  \
        _Pragma("unroll")                                                              \
        for (int j = 0; j < 4; ++j) {                                                  \
            int row = j * 8 + w;                                                       \
            const char* src = gbat + ((size_t)(kv0 + (mc) * 32 + row)) * 1024          \
                              + ((lane * 16) ^ ((row & 7) << 4));                      \
            gload16(src, (char*)&gtile[buf][0] + row * 1024);                          \
        }                                                                              \
    }

    float md[4], sd[4], ms[4], ss[4];
#pragma unroll
    for (int r = 0; r < 4; ++r) { md[r] = -1e30f; sd[r] = 0.f; ms[r] = -1e30f; ss[r] = 0.f; }

    STAGEA(0, 0);
    __syncthreads();
    for (int mc = 0; mc < 64; ++mc) {
        int buf = mc & 1;
        if (mc < 63) STAGEA(buf ^ 1, mc + 1);
        f32x4 acc = {0, 0, 0, 0};
        const char* gt = (const char*)&gtile[buf][0];
#pragma unroll
        for (int kk = 0; kk < 16; ++kk) {
            int row = MB * 16 + l15;
            int y = (kk * 64 + l4 * 16) ^ ((row & 7) << 4);
            short8 gg = *(const short8*)(gt + row * 1024 + y);
            acc = __builtin_amdgcn_mfma_f32_16x16x32_bf16(q[kk], gg, acc, 0, 0, 0);
        }
#pragma unroll
        for (int r = 0; r < 4; ++r) {
            float v = acc[r];
            float mn = fmaxf(md[r], v);
            sd[r] = sd[r] * __expf(md[r] - mn) + __expf(v - mn);
            md[r] = mn;
            float vs = fmaxf(v, 0.f);
            mn = fmaxf(ms[r], vs);
            ss[r] = ss[r] * __expf(ms[r] - mn) + __expf(vs - mn);
            ms[r] = mn;
            int qg = n0 + R * 16 + l4 * 4 + r;
            Lg[((size_t)b * 4096 + qg) * 4096 + kv0 + mc * 32 + MB * 16 + l15] = f2h(v);
        }
        __syncthreads();
    }

    // 16-lane merge per row-group
#pragma unroll
    for (int r = 0; r < 4; ++r) {
#pragma unroll
        for (int k = 1; k < 16; k <<= 1) {
            float mo = __shfl_xor(md[r], k), so = __shfl_xor(sd[r], k);
            float mn = fmaxf(md[r], mo);
            sd[r] = sd[r] * __expf(md[r] - mn) + so * __expf(mo - mn);
            md[r] = mn;
            mo = __shfl_xor(ms[r], k); so = __shfl_xor(ss[r], k);
            mn = fmaxf(ms[r], mo);
            ss[r] = ss[r] * __expf(ms[r] - mn) + so * __expf(mo - mn);
            ms[r] = mn;
        }
    }
    if (l15 == 0) {
#pragma unroll
        for (int r = 0; r < 4; ++r) {
            int row = l4 * 4 + r;
            smd[R][MB][row] = md[r]; ssd_[R][MB][row] = sd[r];
            smsp[R][MB][row] = ms[r]; sssp[R][MB][row] = ss[r];
        }
    }
    __syncthreads();
    if (MB == 0 && l15 == 0) {
#pragma unroll
        for (int r = 0; r < 4; ++r) {
            int row = l4 * 4 + r;
            float m0_ = smd[R][0][row], s0_ = ssd_[R][0][row];
            float m1_ = smd[R][1][row], s1_ = ssd_[R][1][row];
            float mn = fmaxf(m0_, m1_);
            float Sd = s0_ * __expf(m0_ - mn) + s1_ * __expf(m1_ - mn);
            float Md = mn;
            m0_ = smsp[R][0][row]; s0_ = sssp[R][0][row];
            m1_ = smsp[R][1][row]; s1_ = sssp[R][1][row];
            mn = fmaxf(m0_, m1_);
            float Ss = s0_ * __expf(m0_ - mn) + s1_ * __expf(m1_ - mn);
            float Ms = mn;
            int qg = n0 + R * 16 + l4 * 4 + r;
            float4 st = {Md, Sd, Ms, Ss};
            *(float4*)(stats + (((size_t)b * 4096 + qg) * 2 + half) * 4) = st;
        }
    }
#undef STAGEA
}

// ============ kernel B: e = exp(mix of softmaxes) + PV + epilogue (channel-split) ============
// grid 512: b=(bid&7)>>1; g=bid>>3; qt=((bid&1)<<5)|(g>>1); cs=g&1 (channel half).
// 2 blocks/CU. producer: lane owns (q-row = w*8+(lane>>3), kv-octet) -> bf16 e-tile (dbuf).
// consumer: wave w owns 32 mean-channels (cs*256+w*32) + matching 32 sec-channels (+512).
__global__ __launch_bounds__(512, 4) void k_attnB(
    const u16* __restrict__ Lg, const u16* __restrict__ H,
    const float* __restrict__ stats, const float* __restrict__ wmix,
    const float* __restrict__ content, const float* __restrict__ cstat,
    float* __restrict__ out) {

    __shared__ __align__(16) u16 et[2][4096];   // 2 x 8KB bf16 e-tile [64q][64kv]
    __shared__ float zrow[64];

    int bid = blockIdx.x;
    int b = (bid & 7) >> 1;
    int g = bid >> 3;
    int qt = ((bid & 1) << 5) | (g >> 1);
    int cs = g & 1;
    int n0 = qt * 64;
    int lane = threadIdx.x & 63, w = threadIdx.x >> 6;
    int l15 = lane & 15, l4 = lane >> 4;

    float wa = wmix[0], wbv = wmix[1];
    float wmx = fmaxf(wa, wbv);
    float e0 = __expf(wa - wmx), e1 = __expf(wbv - wmx);
    float w0 = e0 / (e0 + e1), w1 = e1 / (e0 + e1);

    // producer identity + merged stats (kv-halves)
    int qlocal = w * 8 + (lane >> 3);
    int kvl = (lane & 7) * 8;
    float md, isd, ms, iss;
    {
        const float* sp = stats + (((size_t)b * 4096 + n0 + qlocal) * 2) * 4;
        float4 s0 = *(const float4*)sp;
        float4 s1 = *(const float4*)(sp + 4);
        float mn = fmaxf(s0.x, s1.x);
        float S = s0.y * __expf(s0.x - mn) + s1.y * __expf(s1.x - mn);
        md = mn; isd = 1.f / S;
        mn = fmaxf(s0.z, s1.z);
        S = s0.w * __expf(s0.z - mn) + s1.w * __expf(s1.z - mn);
        ms = mn; iss = 1.f / S;
    }
    const u16* lgrow = Lg + ((size_t)b * 4096 + n0 + qlocal) * 4096 + kvl;
    unsigned ewbyte = (unsigned)(qlocal * 128) + (((unsigned)(lane & 7) * 16) ^ ((unsigned)(qlocal & 7) << 4));

    float z = 0.f;

#define PRODUCE(buf, mc)                                                               \
    {                                                                                  \
        short8 L8 = *(const short8*)(lgrow + (size_t)(mc) * 64);                       \
        short8 ebf;                                                                    \
        _Pragma("unroll")                                                              \
        for (int j = 0; j < 8; ++j) {                                                  \
            float v = h2f((u16)L8[j]);                                                 \
            float ed = __expf(v - md) * isd;                                           \
            float es = __expf(fmaxf(v, 0.f) - ms) * iss;                               \
            float e = __expf(w0 * ed + w1 * es);                                       \
            z += e;                                                                    \
            ebf[j] = (short)f2bf(e);                                                   \
        }                                                                              \
        *(short8*)((char*)&et[buf][0] + ewbyte) = ebf;                                 \
    }

    f32x4 pv[16];
#pragma unroll
    for (int i = 0; i < 16; ++i) pv[i] = (f32x4){0, 0, 0, 0};

    PRODUCE(0, 0);
    __syncthreads();
    for (int mc = 0; mc < 64; ++mc) {
        int buf = mc & 1;
        if (mc < 63) PRODUCE(buf ^ 1, mc + 1);
        const char* eb = (const char*)&et[buf][0];
        const u16* hb = H + (size_t)b * 1024 * 4096 + (size_t)mc * 64 + l4 * 8;
#pragma unroll
        for (int ks = 0; ks < 2; ++ks) {
            short8 af[4];
#pragma unroll
            for (int qf = 0; qf < 4; ++qf) {
                int qq = qf * 16 + l15;
                int y = (ks * 64 + l4 * 16) ^ ((qq & 7) << 4);
                af[qf] = *(const short8*)(eb + qq * 128 + y);
            }
#pragma unroll
            for (int cf = 0; cf < 4; ++cf) {
                int c = (cf < 2) ? (cs * 256 + w * 32 + cf * 16 + l15)
                                 : (512 + cs * 256 + w * 32 + (cf - 2) * 16 + l15);
                short8 hh = *(const short8*)(hb + (size_t)c * 4096 + ks * 32);
#pragma unroll
                for (int qf = 0; qf < 4; ++qf)
                    pv[qf * 4 + cf] = __builtin_amdgcn_mfma_f32_16x16x32_bf16(af[qf], hh, pv[qf * 4 + cf], 0, 0, 0);
            }
        }
        __syncthreads();
    }

    // Z: reduce the 8 kv-octet lanes of each q-row (contiguous 8 lanes)
    z += __shfl_xor(z, 1);
    z += __shfl_xor(z, 2);
    z += __shfl_xor(z, 4);
    if ((lane & 7) == 0) zrow[qlocal] = z;
    __syncthreads();

    // epilogue: mean/std + fused mean_variance_norm(content), float4 I/O
#pragma unroll
    for (int qf = 0; qf < 4; ++qf) {
        float iz[4];
#pragma unroll
        for (int r = 0; r < 4; ++r)
            iz[r] = 1.f / zrow[qf * 16 + l4 * 4 + r];
#pragma unroll
        for (int cf = 0; cf < 2; ++cf) {
            int c = cs * 256 + w * 32 + cf * 16 + l15;
            float mu = cstat[((size_t)b * 512 + c) * 2];
            float rstd = cstat[((size_t)b * 512 + c) * 2 + 1];
            const float* cp = content + ((size_t)b * 512 + c) * 4096 + n0 + qf * 16 + l4 * 4;
            float* op = out + ((size_t)b * 512 + c) * 4096 + n0 + qf * 16 + l4 * 4;
            float4 cv = *(const float4*)cp;
            float4 ov;
#pragma unroll
            for (int r = 0; r < 4; ++r) {
                float mean = pv[qf * 4 + cf][r] * iz[r];
                float sec = pv[qf * 4 + cf + 2][r] * iz[r];
                float stdv = sqrtf(fmaxf(sec - mean * mean, 0.f));
                (&ov.x)[r] = stdv * ((&cv.x)[r] - mu) * rstd + mean;
            }
            *(float4*)op = ov;
        }
    }
#undef PRODUCE
}

extern "C" void kernel_launch(void* const* d_in, const int* in_sizes, int n_in,
                              void* d_out, int out_size, void* d_ws, size_t ws_size,
                              hipStream_t stream) {
    (void)in_sizes; (void)n_in; (void)out_size; (void)ws_size;
    const float* content = (const float*)d_in[0];
    const float* style   = (const float*)d_in[1];
    const float* ckey    = (const float*)d_in[2];
    const float* skey    = (const float*)d_in[3];
    const float* f_w = (const float*)d_in[4];
    const float* f_b = (const float*)d_in[5];
    const float* g_w = (const float*)d_in[6];
    const float* g_b = (const float*)d_in[7];
    const float* h_w = (const float*)d_in[8];
    const float* h_b = (const float*)d_in[9];
    const float* wmix = (const float*)d_in[10];
    float* out = (float*)d_out;

    const size_t MiB = 1048576;
    char* ws = (char*)d_ws;
    // Prep layout. Hb aliases ckT+skT (dead by convH time; same-stream serialization).
    u16* ckT = (u16*)(ws + 0);
    u16* skT = (u16*)(ws + 16 * MiB);
    u16* stT = (u16*)(ws + 32 * MiB);
    u16* fwB = (u16*)(ws + 48 * MiB);
    u16* gwB = (u16*)(ws + 48 * MiB + 524288);
    u16* hwB = (u16*)(ws + 49 * MiB);
    float* cst = (float*)(ws + 49 * MiB + 524288);   // 16 KB
    u16* Qb  = (u16*)(ws + 50 * MiB);
    u16* Gb  = (u16*)(ws + 66 * MiB);
    u16* Hb  = (u16*)(ws + 0);
    // fp16 logits [4][4096][4096] (128 MiB) + stats (512 KB); ws_size >= 210.6 MB
    // confirmed by round-5 run (split path executed: k_attnA/k_attnB in counters).
    u16* Lg  = (u16*)(ws + 82 * MiB);
    float* stats = (float*)(ws + 210 * MiB);

    k_cast3<<<768, 256, 0, stream>>>(f_w, g_w, h_w, fwB, gwB, hwB);
    k_transpose<<<dim3(64, 8, 4), 256, 0, stream>>>(ckey, ckT);
    k_transpose<<<dim3(64, 8, 4), 256, 0, stream>>>(skey, skT);
    k_transpose<<<dim3(64, 8, 4), 256, 0, stream>>>(style, stT);
    k_cstats<<<dim3(512, 4), 256, 0, stream>>>(content, cst);
    k_convP<<<dim3(2048), 256, 0, stream>>>(ckT, fwB, f_b, Qb);
    k_convP<<<dim3(2048), 256, 0, stream>>>(skT, gwB, g_b, Gb);
    k_convH<<<dim3(2048), 256, 0, stream>>>(stT, hwB, h_b, Hb);
    k_attnA<<<dim3(512), 512, 0, stream>>>(Qb, Gb, Lg, stats);
    k_attnB<<<dim3(512), 512, 0, stream>>>(Lg, Hb, stats, wmix, content, cst, out);
}

// Round 7
// 760.403 us; speedup vs baseline: 3.3497x; 1.0322x over previous
//
#include <hip/hip_runtime.h>
#include <hip/hip_bf16.h>
#include <hip/hip_fp16.h>
#include <stdint.h>

typedef float f32x4 __attribute__((ext_vector_type(4)));
typedef short short8 __attribute__((ext_vector_type(8)));
typedef unsigned short ushort4_t __attribute__((ext_vector_type(4)));
typedef unsigned short u16;

static __device__ __forceinline__ u16 f2bf(float f) {
    __hip_bfloat16 h = __float2bfloat16(f);
    return *reinterpret_cast<const u16*>(&h);
}
static __device__ __forceinline__ u16 f2h(float f) {
    __half h = __float2half(f);
    return *reinterpret_cast<const u16*>(&h);
}
static __device__ __forceinline__ float h2f(u16 b) {
    __half h = *reinterpret_cast<const __half*>(&b);
    return __half2float(h);
}

// async global->LDS, 16B per lane: LDS dest = wave-uniform base + lane*16,
// global src is per-lane (carries the swizzle).
static __device__ __forceinline__ void gload16(const void* g, void* l) {
    __builtin_amdgcn_global_load_lds((const __attribute__((address_space(1))) void*)g,
                                     (__attribute__((address_space(3))) void*)l, 16, 0, 0);
}

// ---------------- weights f32 -> bf16 cast, 3 arrays in one launch ----------------
__global__ void k_cast3(const float* __restrict__ a, const float* __restrict__ b,
                        const float* __restrict__ c, u16* __restrict__ oa,
                        u16* __restrict__ ob, u16* __restrict__ oc) {
    int i = blockIdx.x * blockDim.x + threadIdx.x;   // 3*65536 float4-groups
    int which = i >> 16, j = i & 65535;
    const float* in = (which == 0) ? a : (which == 1) ? b : c;
    u16* out = (which == 0) ? oa : (which == 1) ? ob : oc;
    float4 v = ((const float4*)in)[j];
    ushort4 o;
    o.x = f2bf(v.x); o.y = f2bf(v.y); o.z = f2bf(v.z); o.w = f2bf(v.w);
    ((ushort4*)out)[j] = o;
}

// ------------- transpose+cast: f32 [b][512][4096] -> bf16 [b][4096][512] -------------
__global__ __launch_bounds__(256) void k_transpose(const float* __restrict__ in, u16* __restrict__ out) {
    __shared__ float t[64][65];
    int b = blockIdx.z;
    int c0 = blockIdx.y * 64;
    int n0 = blockIdx.x * 64;
    const float* ip = in + ((size_t)b * 512 + c0) * 4096 + n0;
#pragma unroll
    for (int i = 0; i < 16; ++i) {
        int idx = threadIdx.x + i * 256;
        int cl = idx >> 6, nl = idx & 63;
        t[cl][nl] = ip[(size_t)cl * 4096 + nl];
    }
    __syncthreads();
    u16* op = out + ((size_t)b * 4096 + n0) * 512 + c0;
#pragma unroll
    for (int i = 0; i < 16; ++i) {
        int idx = threadIdx.x + i * 256;
        int nr = idx >> 6, cc = idx & 63;
        op[(size_t)nr * 512 + cc] = f2bf(t[cc][nr]);
    }
}

// ------------- content per-(b,c) mean / rstd (ddof=1, +eps) -------------
__global__ __launch_bounds__(256) void k_cstats(const float* __restrict__ content, float* __restrict__ cstat) {
    int c = blockIdx.x, b = blockIdx.y;
    const float4* r4 = (const float4*)(content + ((size_t)b * 512 + c) * 4096);
    float s = 0.f, ss = 0.f;
    for (int i = threadIdx.x; i < 1024; i += 256) {
        float4 v = r4[i];
        s += v.x + v.y + v.z + v.w;
        ss += v.x * v.x + v.y * v.y + v.z * v.z + v.w * v.w;
    }
#pragma unroll
    for (int k = 1; k < 64; k <<= 1) { s += __shfl_xor(s, k); ss += __shfl_xor(ss, k); }
    __shared__ float ls[4], lss[4];
    int w = threadIdx.x >> 6;
    if ((threadIdx.x & 63) == 0) { ls[w] = s; lss[w] = ss; }
    __syncthreads();
    if (threadIdx.x == 0) {
        s = ls[0] + ls[1] + ls[2] + ls[3];
        ss = lss[0] + lss[1] + lss[2] + lss[3];
        float mu = s / 4096.f;
        float var = (ss - 4096.f * mu * mu) / 4095.f;
        cstat[((size_t)b * 512 + c) * 2] = mu;
        cstat[((size_t)b * 512 + c) * 2 + 1] = rsqrtf(var + 1e-5f);
    }
}

// ------------- conv1x1, pixel-major output, XCD-pinned batches -------------
__global__ __launch_bounds__(256) void k_convP(const u16* __restrict__ XT, const u16* __restrict__ Wb,
                                               const float* __restrict__ bias, u16* __restrict__ out) {
    int bid = blockIdx.x;
    int b = (bid & 7) >> 1;
    int u = ((bid & 1) << 8) | (bid >> 3);
    int n0 = (u & 63) * 64, o0 = (u >> 6) * 64;
    int lane = threadIdx.x & 63, w = threadIdx.x >> 6;
    int l15 = lane & 15, l4 = lane >> 4;
    const u16* ap = XT + ((size_t)b * 4096 + n0 + w * 16 + l15) * 512 + l4 * 8;
    f32x4 acc[4] = {{0,0,0,0},{0,0,0,0},{0,0,0,0},{0,0,0,0}};
#pragma unroll
    for (int kk = 0; kk < 16; ++kk) {
        short8 a = *(const short8*)(ap + kk * 32);
#pragma unroll
        for (int bo = 0; bo < 4; ++bo) {
            const u16* bp = Wb + ((size_t)(o0 + bo * 16 + l15)) * 512 + kk * 32 + l4 * 8;
            short8 bb = *(const short8*)bp;
            acc[bo] = __builtin_amdgcn_mfma_f32_16x16x32_bf16(a, bb, acc[bo], 0, 0, 0);
        }
    }
#pragma unroll
    for (int bo = 0; bo < 4; ++bo) {
        float bv = bias[o0 + bo * 16 + l15];
#pragma unroll
        for (int r = 0; r < 4; ++r) {
            int n = n0 + w * 16 + l4 * 4 + r;
            out[((size_t)b * 4096 + n) * 512 + o0 + bo * 16 + l15] = f2bf(acc[bo][r] + bv);
        }
    }
}

// ------------- conv1x1, channel-major output + squares, XCD-pinned batches -------------
__global__ __launch_bounds__(256) void k_convH(const u16* __restrict__ ST, const u16* __restrict__ Wb,
                                               const float* __restrict__ bias, u16* __restrict__ out) {
    int bid = blockIdx.x;
    int b = (bid & 7) >> 1;
    int u = ((bid & 1) << 8) | (bid >> 3);
    int m0 = (u & 63) * 64, o0 = (u >> 6) * 64;
    int lane = threadIdx.x & 63, w = threadIdx.x >> 6;
    int l15 = lane & 15, l4 = lane >> 4;
    const u16* ap = Wb + ((size_t)(o0 + w * 16 + l15)) * 512 + l4 * 8;
    f32x4 acc[4] = {{0,0,0,0},{0,0,0,0},{0,0,0,0},{0,0,0,0}};
#pragma unroll
    for (int kk = 0; kk < 16; ++kk) {
        short8 a = *(const short8*)(ap + kk * 32);
#pragma unroll
        for (int mb = 0; mb < 4; ++mb) {
            const u16* bp = ST + ((size_t)b * 4096 + m0 + mb * 16 + l15) * 512 + kk * 32 + l4 * 8;
            short8 bb = *(const short8*)bp;
            acc[mb] = __builtin_amdgcn_mfma_f32_16x16x32_bf16(a, bb, acc[mb], 0, 0, 0);
        }
    }
#pragma unroll
    for (int r = 0; r < 4; ++r) {
        int o = o0 + w * 16 + l4 * 4 + r;
        float bv = bias[o];
#pragma unroll
        for (int mb = 0; mb < 4; ++mb) {
            float v = acc[mb][r] + bv;
            size_t base = ((size_t)b * 1024 + o) * 4096 + m0 + mb * 16 + l15;
            out[base] = f2bf(v);
            out[base + (size_t)512 * 4096] = f2bf(v * v);
        }
    }
}

// ============ kernel A: QK (swapped operands) + softmax stats + fp16 logits ============
// grid 512: b=(bid&7)>>1; half=bid&1 (PINNED to XCD: per-XCD G slice = 2 MB, L2-resident);
// qt=bid>>3 (0..63). 8 waves: R=w>>1 (16 q-rows via B-operand cols), MB=w&1 (kv 16-half).
// mfma(G,Q): D row = kv (lane's 4 consecutive), col = q (l15) -> per-lane scalar stats,
// packed 8B fp16 logit stores.
__global__ __launch_bounds__(512, 4) void k_attnA(
    const u16* __restrict__ Q, const u16* __restrict__ G,
    u16* __restrict__ Lg, float* __restrict__ stats) {

    __shared__ __align__(16) u16 gtile[2][32 * 512];   // 2 x 32KB
    __shared__ float smd[4][2][16], ssd_[4][2][16], smsp[4][2][16], sssp[4][2][16];

    int bid = blockIdx.x;
    int b = (bid & 7) >> 1;
    int half = bid & 1;
    int qt = bid >> 3;
    int n0 = qt * 64;
    int kv0 = half * 2048;
    int lane = threadIdx.x & 63, w = threadIdx.x >> 6;
    int l15 = lane & 15, l4 = lane >> 4;
    int R = w >> 1, MB = w & 1;

    const u16* qp = Q + ((size_t)b * 4096 + n0 + R * 16 + l15) * 512 + l4 * 8;
    short8 q[16];
#pragma unroll
    for (int kk = 0; kk < 16; ++kk) q[kk] = *(const short8*)(qp + kk * 32);

    const char* gbat = (const char*)(G + (size_t)b * 4096 * 512);
    // lane's logit row/cols: q-row = n0+R*16+l15, kv = kv0 + mc*32 + MB*16 + l4*4 .. +3
    size_t lgoff = ((size_t)b * 4096 + n0 + R * 16 + l15) * 4096 + kv0 + MB * 16 + l4 * 4;

#define STAGEA(buf, mc)                                                                \
    {                                                                                  \
        _Pragma("unroll")                                                              \
        for (int j = 0; j < 4; ++j) {                                                  \
            int row = j * 8 + w;                                                       \
            const char* src = gbat + ((size_t)(kv0 + (mc) * 32 + row)) * 1024          \
                              + ((lane * 16) ^ ((row & 7) << 4));                      \
            gload16(src, (char*)&gtile[buf][0] + row * 1024);                          \
        }                                                                              \
    }

    float md = -1e30f, sd = 0.f, ms = -1e30f, ss = 0.f;

    STAGEA(0, 0);
    __syncthreads();
    for (int mc = 0; mc < 64; ++mc) {
        int buf = mc & 1;
        if (mc < 63) STAGEA(buf ^ 1, mc + 1);
        f32x4 acc = {0, 0, 0, 0};
        const char* gt = (const char*)&gtile[buf][0];
        int row = MB * 16 + l15;
#pragma unroll
        for (int kk = 0; kk < 16; ++kk) {
            int y = (kk * 64 + l4 * 16) ^ ((row & 7) << 4);
            short8 gg = *(const short8*)(gt + row * 1024 + y);
            acc = __builtin_amdgcn_mfma_f32_16x16x32_bf16(gg, q[kk], acc, 0, 0, 0);
        }
        float v0 = acc[0], v1 = acc[1], v2 = acc[2], v3 = acc[3];
        float mx = fmaxf(fmaxf(v0, v1), fmaxf(v2, v3));
        float mn = fmaxf(md, mx);
        sd = sd * __expf(md - mn) +
             ((__expf(v0 - mn) + __expf(v1 - mn)) + (__expf(v2 - mn) + __expf(v3 - mn)));
        md = mn;
        float mns = fmaxf(ms, fmaxf(mx, 0.f));
        ss = ss * __expf(ms - mns) +
             ((__expf(fmaxf(v0, 0.f) - mns) + __expf(fmaxf(v1, 0.f) - mns)) +
              (__expf(fmaxf(v2, 0.f) - mns) + __expf(fmaxf(v3, 0.f) - mns)));
        ms = mns;
        ushort4_t pk = {f2h(v0), f2h(v1), f2h(v2), f2h(v3)};
        *(ushort4_t*)(Lg + lgoff + (size_t)mc * 32) = pk;
        __syncthreads();
    }

    // merge the 4 l4-groups (same q-row): xor 16, 32
#pragma unroll
    for (int k = 16; k < 64; k <<= 1) {
        float mo = __shfl_xor(md, k), so = __shfl_xor(sd, k);
        float mn = fmaxf(md, mo);
        sd = sd * __expf(md - mn) + so * __expf(mo - mn);
        md = mn;
        mo = __shfl_xor(ms, k); so = __shfl_xor(ss, k);
        mn = fmaxf(ms, mo);
        ss = ss * __expf(ms - mn) + so * __expf(mo - mn);
        ms = mn;
    }
    if (l4 == 0) {
        smd[R][MB][l15] = md; ssd_[R][MB][l15] = sd;
        smsp[R][MB][l15] = ms; sssp[R][MB][l15] = ss;
    }
    __syncthreads();
    if (MB == 0 && lane < 16) {
        float m0_ = smd[R][0][l15], s0_ = ssd_[R][0][l15];
        float m1_ = smd[R][1][l15], s1_ = ssd_[R][1][l15];
        float mn = fmaxf(m0_, m1_);
        float Sd = s0_ * __expf(m0_ - mn) + s1_ * __expf(m1_ - mn);
        float Md = mn;
        m0_ = smsp[R][0][l15]; s0_ = sssp[R][0][l15];
        m1_ = smsp[R][1][l15]; s1_ = sssp[R][1][l15];
        mn = fmaxf(m0_, m1_);
        float Ss = s0_ * __expf(m0_ - mn) + s1_ * __expf(m1_ - mn);
        float Ms = mn;
        int qg = n0 + R * 16 + l15;
        float4 st = {Md, Sd, Ms, Ss};
        *(float4*)(stats + (((size_t)b * 4096 + qg) * 2 + half) * 4) = st;
    }
#undef STAGEA
}

// ============ kernel B: e = exp(mix of softmaxes) + PV + epilogue (channel-split) ============
// grid 512: b=(bid&7)>>1; cs=bid&1 (PINNED to XCD: per-XCD H slice = 512 ch = 4 MB,
// L2-resident); qt=bid>>3. 2 blocks/CU.
__global__ __launch_bounds__(512, 4) void k_attnB(
    const u16* __restrict__ Lg, const u16* __restrict__ H,
    const float* __restrict__ stats, const float* __restrict__ wmix,
    const float* __restrict__ content, const float* __restrict__ cstat,
    float* __restrict__ out) {

    __shared__ __align__(16) u16 et[2][4096];   // 2 x 8KB bf16 e-tile [64q][64kv]
    __shared__ float zrow[64];

    int bid = blockIdx.x;
    int b = (bid & 7) >> 1;
    int cs = bid & 1;
    int qt = bid >> 3;
    int n0 = qt * 64;
    int lane = threadIdx.x & 63, w = threadIdx.x >> 6;
    int l15 = lane & 15, l4 = lane >> 4;

    float wa = wmix[0], wbv = wmix[1];
    float wmx = fmaxf(wa, wbv);
    float e0 = __expf(wa - wmx), e1 = __expf(wbv - wmx);
    float w0 = e0 / (e0 + e1), w1 = e1 / (e0 + e1);

    // producer identity + merged stats (kv-halves)
    int qlocal = w * 8 + (lane >> 3);
    int kvl = (lane & 7) * 8;
    float md, isd, ms, iss;
    {
        const float* sp = stats + (((size_t)b * 4096 + n0 + qlocal) * 2) * 4;
        float4 s0 = *(const float4*)sp;
        float4 s1 = *(const float4*)(sp + 4);
        float mn = fmaxf(s0.x, s1.x);
        float S = s0.y * __expf(s0.x - mn) + s1.y * __expf(s1.x - mn);
        md = mn; isd = 1.f / S;
        mn = fmaxf(s0.z, s1.z);
        S = s0.w * __expf(s0.z - mn) + s1.w * __expf(s1.z - mn);
        ms = mn; iss = 1.f / S;
    }
    const u16* lgrow = Lg + ((size_t)b * 4096 + n0 + qlocal) * 4096 + kvl;
    unsigned ewbyte = (unsigned)(qlocal * 128) + (((unsigned)(lane & 7) * 16) ^ ((unsigned)(qlocal & 7) << 4));

    float z = 0.f;

#define PRODUCE(buf, mc)                                                               \
    {                                                                                  \
        short8 L8 = *(const short8*)(lgrow + (size_t)(mc) * 64);                       \
        short8 ebf;                                                                    \
        _Pragma("unroll")                                                              \
        for (int j = 0; j < 8; ++j) {                                                  \
            float v = h2f((u16)L8[j]);                                                 \
            float ed = __expf(v - md) * isd;                                           \
            float es = __expf(fmaxf(v, 0.f) - ms) * iss;                               \
            float e = __expf(w0 * ed + w1 * es);                                       \
            z += e;                                                                    \
            ebf[j] = (short)f2bf(e);                                                   \
        }                                                                              \
        *(short8*)((char*)&et[buf][0] + ewbyte) = ebf;                                 \
    }

    f32x4 pv[16];
#pragma unroll
    for (int i = 0; i < 16; ++i) pv[i] = (f32x4){0, 0, 0, 0};

    PRODUCE(0, 0);
    __syncthreads();
    for (int mc = 0; mc < 64; ++mc) {
        int buf = mc & 1;
        if (mc < 63) PRODUCE(buf ^ 1, mc + 1);
        const char* eb = (const char*)&et[buf][0];
        const u16* hb = H + (size_t)b * 1024 * 4096 + (size_t)mc * 64 + l4 * 8;
#pragma unroll
        for (int ks = 0; ks < 2; ++ks) {
            short8 af[4];
#pragma unroll
            for (int qf = 0; qf < 4; ++qf) {
                int qq = qf * 16 + l15;
                int y = (ks * 64 + l4 * 16) ^ ((qq & 7) << 4);
                af[qf] = *(const short8*)(eb + qq * 128 + y);
            }
#pragma unroll
            for (int cf = 0; cf < 4; ++cf) {
                int c = (cf < 2) ? (cs * 256 + w * 32 + cf * 16 + l15)
                                 : (512 + cs * 256 + w * 32 + (cf - 2) * 16 + l15);
                short8 hh = *(const short8*)(hb + (size_t)c * 4096 + ks * 32);
#pragma unroll
                for (int qf = 0; qf < 4; ++qf)
                    pv[qf * 4 + cf] = __builtin_amdgcn_mfma_f32_16x16x32_bf16(af[qf], hh, pv[qf * 4 + cf], 0, 0, 0);
            }
        }
        __syncthreads();
    }

    // Z: reduce the 8 kv-octet lanes of each q-row (contiguous 8 lanes)
    z += __shfl_xor(z, 1);
    z += __shfl_xor(z, 2);
    z += __shfl_xor(z, 4);
    if ((lane & 7) == 0) zrow[qlocal] = z;
    __syncthreads();

    // epilogue: mean/std + fused mean_variance_norm(content), float4 I/O
#pragma unroll
    for (int qf = 0; qf < 4; ++qf) {
        float iz[4];
#pragma unroll
        for (int r = 0; r < 4; ++r)
            iz[r] = 1.f / zrow[qf * 16 + l4 * 4 + r];
#pragma unroll
        for (int cf = 0; cf < 2; ++cf) {
            int c = cs * 256 + w * 32 + cf * 16 + l15;
            float mu = cstat[((size_t)b * 512 + c) * 2];
            float rstd = cstat[((size_t)b * 512 + c) * 2 + 1];
            const float* cp = content + ((size_t)b * 512 + c) * 4096 + n0 + qf * 16 + l4 * 4;
            float* op = out + ((size_t)b * 512 + c) * 4096 + n0 + qf * 16 + l4 * 4;
            float4 cv = *(const float4*)cp;
            float4 ov;
#pragma unroll
            for (int r = 0; r < 4; ++r) {
                float mean = pv[qf * 4 + cf][r] * iz[r];
                float sec = pv[qf * 4 + cf + 2][r] * iz[r];
                float stdv = sqrtf(fmaxf(sec - mean * mean, 0.f));
                (&ov.x)[r] = stdv * ((&cv.x)[r] - mu) * rstd + mean;
            }
            *(float4*)op = ov;
        }
    }
#undef PRODUCE
}

extern "C" void kernel_launch(void* const* d_in, const int* in_sizes, int n_in,
                              void* d_out, int out_size, void* d_ws, size_t ws_size,
                              hipStream_t stream) {
    (void)in_sizes; (void)n_in; (void)out_size; (void)ws_size;
    const float* content = (const float*)d_in[0];
    const float* style   = (const float*)d_in[1];
    const float* ckey    = (const float*)d_in[2];
    const float* skey    = (const float*)d_in[3];
    const float* f_w = (const float*)d_in[4];
    const float* f_b = (const float*)d_in[5];
    const float* g_w = (const float*)d_in[6];
    const float* g_b = (const float*)d_in[7];
    const float* h_w = (const float*)d_in[8];
    const float* h_b = (const float*)d_in[9];
    const float* wmix = (const float*)d_in[10];
    float* out = (float*)d_out;

    const size_t MiB = 1048576;
    char* ws = (char*)d_ws;
    // Prep layout. Hb aliases ckT+skT (dead by convH time; same-stream serialization).
    u16* ckT = (u16*)(ws + 0);
    u16* skT = (u16*)(ws + 16 * MiB);
    u16* stT = (u16*)(ws + 32 * MiB);
    u16* fwB = (u16*)(ws + 48 * MiB);
    u16* gwB = (u16*)(ws + 48 * MiB + 524288);
    u16* hwB = (u16*)(ws + 49 * MiB);
    float* cst = (float*)(ws + 49 * MiB + 524288);   // 16 KB
    u16* Qb  = (u16*)(ws + 50 * MiB);
    u16* Gb  = (u16*)(ws + 66 * MiB);
    u16* Hb  = (u16*)(ws + 0);
    // fp16 logits [4][4096][4096] (128 MiB) + stats (512 KB); ws_size >= 210.6 MB
    // confirmed by round-5/6 runs (split path executed).
    u16* Lg  = (u16*)(ws + 82 * MiB);
    float* stats = (float*)(ws + 210 * MiB);

    k_cast3<<<768, 256, 0, stream>>>(f_w, g_w, h_w, fwB, gwB, hwB);
    k_transpose<<<dim3(64, 8, 4), 256, 0, stream>>>(ckey, ckT);
    k_transpose<<<dim3(64, 8, 4), 256, 0, stream>>>(skey, skT);
    k_transpose<<<dim3(64, 8, 4), 256, 0, stream>>>(style, stT);
    k_cstats<<<dim3(512, 4), 256, 0, stream>>>(content, cst);
    k_convP<<<dim3(2048), 256, 0, stream>>>(ckT, fwB, f_b, Qb);
    k_convP<<<dim3(2048), 256, 0, stream>>>(skT, gwB, g_b, Gb);
    k_convH<<<dim3(2048), 256, 0, stream>>>(stT, hwB, h_b, Hb);
    k_attnA<<<dim3(512), 512, 0, stream>>>(Qb, Gb, Lg, stats);
    k_attnB<<<dim3(512), 512, 0, stream>>>(Lg, Hb, stats, wmix, content, cst, out);
}